// Round 13
// baseline (486.264 us; speedup 1.0000x reference)
//
#include <hip/hip_runtime.h>
#include <hip/hip_bf16.h>

#define NB 4       // batch
#define SEQ 1024
#define EMB 1024
#define NH 16
#define HD 64
#define GRID 768   // persistent blocks; __launch_bounds__(256,3) guarantees 3/CU co-residency

typedef unsigned short u16;
typedef __attribute__((ext_vector_type(8))) __bf16 bf16x8;
typedef __attribute__((ext_vector_type(8))) short short8;
typedef __attribute__((ext_vector_type(4))) float floatx4;

__device__ inline u16 f2b_rn(float f) {
    union { float f; unsigned int i; } x; x.f = f;
    unsigned int r = (x.i + 0x7FFFu + ((x.i >> 16) & 1u)) >> 16;
    return (u16)r;
}
__device__ inline bf16x8 s2b(short8 v) {
    union { short8 s; bf16x8 b; } x; x.s = v; return x.b;
}
__device__ inline void gload_lds16(const void* g, void* l) {
    __builtin_amdgcn_global_load_lds(
        (const __attribute__((address_space(1))) void*)g,
        (__attribute__((address_space(3))) void*)l, 16, 0, 0);
}
// XOR-swizzled fragment read from an unpadded [rows][64] u16 LDS buffer.
__device__ inline bf16x8 ldsfrag(const u16* base, int r, int c) {
    return s2b(*(const short8*)&base[r * 64 + (c ^ ((r & 7) * 8))]);
}
__device__ inline void cvt8(const float* __restrict__ s, u16* __restrict__ d) {
    float4 a = *(const float4*)(s);
    float4 b = *(const float4*)(s + 4);
    union { u16 u[8]; int4 v; } o;
    o.u[0] = f2b_rn(a.x); o.u[1] = f2b_rn(a.y); o.u[2] = f2b_rn(a.z); o.u[3] = f2b_rn(a.w);
    o.u[4] = f2b_rn(b.x); o.u[5] = f2b_rn(b.y); o.u[6] = f2b_rn(b.z); o.u[7] = f2b_rn(b.w);
    *(int4*)(d) = o.v;
}

// device-scope grid barrier: release fence + atomic arrive + spin + acquire fence
__device__ inline void grid_sync(unsigned int* cnt, unsigned int target) {
    __syncthreads();
    if (threadIdx.x == 0) {
        __threadfence();                        // release (L2 writeback, device scope)
        atomicAdd(cnt, 1u);                     // device-scope by default [m20]
        while (atomicAdd(cnt, 0u) < target) __builtin_amdgcn_s_sleep(8);
        __threadfence();                        // acquire (invalidate stale lines)
    }
    __syncthreads();
}

union SharedU {
    u16 T[64 * 80];                                              // P0 transpose: 10 KB
    struct { u16 As[128 * 64]; u16 Bs[128 * 64]; } g;            // P1 qkv: 32 KB
    struct { u16 Ks[64 * 64]; u16 Vs[80 * 64]; u16 Ps[128 * 72]; } a; // P2 attn: 36 KB
    struct { u16 As[64 * 64]; u16 Bs[128 * 64]; } p;             // P3 out_proj: 24 KB
};

// ---------------------------------------------------------------------------
// Single persistent kernel: 4 phases separated by grid barriers.
// ---------------------------------------------------------------------------
__global__ __launch_bounds__(256, 3) void fused_mha(
    const float* __restrict__ x, const int* __restrict__ mask,
    const float* __restrict__ Wq, const float* __restrict__ Wk, const float* __restrict__ Wv,
    const float* __restrict__ Wo,
    const float* __restrict__ bq, const float* __restrict__ bk, const float* __restrict__ bv,
    const float* __restrict__ bo,
    u16* __restrict__ xb, u16* __restrict__ Wt, u16* __restrict__ Wob,
    unsigned long long* __restrict__ bits,
    u16* __restrict__ Q, u16* __restrict__ K, u16* __restrict__ Vt,
    u16* __restrict__ Ao, float* __restrict__ Out,
    unsigned int* __restrict__ cnt)
{
    __shared__ SharedU lds;
    int bid = blockIdx.x;
    int tid = threadIdx.x;
    int lane = tid & 63, quad = lane >> 4, ln = lane & 15;
    int w = tid >> 6;

    // ================= P0: prep (x/Wo convert, W transpose, mask ballots) ===
    {
        // W transpose+convert: 768 units, 1 per block
        int e0 = (bid & 15) * 64;
        int ph = bid >> 4;              // 0..47
        int p = ph >> 4, h = ph & 15;
        const float* W = (p == 0 ? Wq : (p == 1 ? Wk : Wv)) + h * (EMB * HD);
        #pragma unroll
        for (int c = 0; c < 2; ++c) {
            int flat = c * 2048 + tid * 8;
            int r = flat >> 6;
            int d = flat & 63;
            cvt8(W + (size_t)(e0 + r) * HD + d, &lds.T[r * 80 + d]);
        }
        __syncthreads();
        int d = tid >> 2;
        int ec = tid & 3;
        union { u16 u[16]; int4 v[2]; } tmp;
        #pragma unroll
        for (int i = 0; i < 16; ++i) tmp.u[i] = lds.T[(ec * 16 + i) * 80 + d];
        u16* dst = Wt + ((size_t)(p * NH + h) * HD + d) * EMB + e0 + ec * 16;
        *(int4*)(dst) = tmp.v[0];
        *(int4*)(dst + 8) = tmp.v[1];

        // x fp32->bf16: 512 units x 4 chunks
        if (bid < 512) {
            #pragma unroll
            for (int c = 0; c < 4; ++c) {
                int i = (bid * 4 + c) * 2048 + tid * 8;
                cvt8(x + i, xb + i);
            }
            // Wo fp32->bf16: 512 units
            int i = bid * 2048 + tid * 8;
            cvt8(Wo + i, Wob + i);
        }
        // mask ballots: 4096 units x 16 rows (4 rows/wave)
        for (int u = bid; u < 4096; u += GRID) {
            int base = u * 16 + w * 4;
            #pragma unroll
            for (int i = 0; i < 4; ++i) {
                int gw = base + i;                    // 0..65535
                int m = mask[(size_t)gw * 64 + lane];
                unsigned long long bl = __ballot(m != 0);
                if (lane == 0) bits[gw] = bl;
            }
        }
    }
    grid_sync(cnt, GRID);

    // ================= P1: QKV GEMM — exactly 768 tiles, 1 per block ========
    {
        u16* As = lds.g.As;
        u16* Bs = lds.g.Bs;
        int n0 = (bid % 24) * 128;
        int m0 = (bid / 24) * 128;
        int wm = w & 1, wn = w >> 1;

        floatx4 acc[4][4] = {};

        for (int k0 = 0; k0 < EMB; k0 += 64) {
            __syncthreads();
            #pragma unroll
            for (int i = 0; i < 4; ++i) {
                int flat0 = i * 256 + (tid & 192);
                int flat = flat0 + lane;
                int r = flat >> 3;
                int c = ((flat & 7) ^ (r & 7)) * 8;
                gload_lds16(xb + (size_t)(m0 + r) * EMB + k0 + c, As + flat0 * 8);
                gload_lds16(Wt + (size_t)(n0 + r) * EMB + k0 + c, Bs + flat0 * 8);
            }
            __syncthreads();

            #pragma unroll
            for (int kk = 0; kk < 2; ++kk) {
                bf16x8 a[4], bf[4];
                #pragma unroll
                for (int mt = 0; mt < 4; ++mt)
                    a[mt] = ldsfrag(As, wm * 64 + mt * 16 + ln, kk * 32 + quad * 8);
                #pragma unroll
                for (int nc = 0; nc < 4; ++nc)
                    bf[nc] = ldsfrag(Bs, wn * 64 + nc * 16 + ln, kk * 32 + quad * 8);
                #pragma unroll
                for (int mt = 0; mt < 4; ++mt)
                    #pragma unroll
                    for (int nc = 0; nc < 4; ++nc)
                        acc[mt][nc] = __builtin_amdgcn_mfma_f32_16x16x32_bf16(a[mt], bf[nc], acc[mt][nc], 0, 0, 0);
            }
        }

        int p = n0 >> 10;
        const float* bias = (p == 0 ? bq : (p == 1 ? bk : bv));
        if (p < 2) {
            u16* Outp = (p == 0) ? Q : K;
            float qs = (p == 0) ? 0.125f * 1.44269504f : 1.0f;  // 1/sqrt(64) * log2(e)
            #pragma unroll
            for (int nc = 0; nc < 4; ++nc) {
                int n = n0 + wn * 64 + nc * 16 + ln;
                int h = (n >> 6) & 15, d = n & 63;
                float bv_ = bias[n & 1023];
                #pragma unroll
                for (int mt = 0; mt < 4; ++mt) {
                    #pragma unroll
                    for (int reg = 0; reg < 4; ++reg) {
                        int m = m0 + wm * 64 + mt * 16 + quad * 4 + reg;
                        int b_ = m >> 10, s = m & 1023;
                        Outp[((size_t)(b_ * NH + h) * SEQ + s) * HD + d] = f2b_rn((acc[mt][nc][reg] + bv_) * qs);
                    }
                }
            }
        } else {
            #pragma unroll
            for (int nc = 0; nc < 4; ++nc) {
                int n = n0 + wn * 64 + nc * 16 + ln;
                int h = (n >> 6) & 15, d = n & 63;
                float bv_ = bias[n & 1023];
                #pragma unroll
                for (int mt = 0; mt < 4; ++mt) {
                    int m = m0 + wm * 64 + mt * 16 + quad * 4;
                    int b_ = m >> 10, s = m & 1023;
                    union { u16 u[4]; uint2 v; } pk;
                    #pragma unroll
                    for (int reg = 0; reg < 4; ++reg)
                        pk.u[reg] = f2b_rn(acc[mt][nc][reg] + bv_);
                    *(uint2*)&Vt[((size_t)(b_ * NH + h) * HD + d) * SEQ + s] = pk.v;
                }
            }
        }
    }
    grid_sync(cnt, 2 * GRID);

    // ================= P2: attention — 512 units (bh, 128-row q-tile) =======
    // 4 waves share one K/V staging (halves staging vs v3); each wave owns
    // 2 strips of 16 q-rows.  S^T = K Q^T; P = exp2; l via ones-row in V.
    if (bid < 512) {
        u16* Ks = lds.a.Ks;
        u16* Vs = lds.a.Vs;
        u16* Ps = lds.a.Ps;
        const int PP = 72;

        int bh = bid & 63;
        int q0 = (bid >> 6) * 128;
        int b = bh >> 4, h = bh & 15;
        const u16* Qb = Q  + (size_t)bh * SEQ * HD;
        const u16* Kb = K  + (size_t)bh * SEQ * HD;
        const u16* Vb = Vt + (size_t)bh * HD * SEQ;   // [d][s]

        if (tid < 16) *(uint2*)&Vs[64 * 64 + tid * 4] = make_uint2(0x3F803F80u, 0x3F803F80u);

        bf16x8 qf[2][2];
        #pragma unroll
        for (int s = 0; s < 2; ++s) {
            const u16* qp = Qb + (size_t)(q0 + w * 32 + s * 16 + ln) * HD + quad * 8;
            union { int4 i; bf16x8 b; } c0, c1;
            c0.i = *(const int4*)(qp);
            c1.i = *(const int4*)(qp + 32);
            qf[s][0] = c0.b; qf[s][1] = c1.b;
        }

        floatx4 o[2][5] = {};

        for (int tt = 0; tt < SEQ / 64; ++tt) {
            int t0 = tt * 64;
            __syncthreads();
            #pragma unroll
            for (int i = 0; i < 2; ++i) {
                int flat0 = i * 256 + (tid & 192);
                int flat = flat0 + lane;
                int r = flat >> 3;
                int c = ((flat & 7) ^ (r & 7)) * 8;
                gload_lds16(Kb + (size_t)(t0 + r) * HD + c, Ks + flat0 * 8);
                gload_lds16(Vb + (size_t)r * SEQ + t0 + c, Vs + flat0 * 8);
            }
            __syncthreads();

            floatx4 sc[2][4] = {};
            #pragma unroll
            for (int kk = 0; kk < 2; ++kk) {
                bf16x8 kf[4];
                #pragma unroll
                for (int tb = 0; tb < 4; ++tb)
                    kf[tb] = ldsfrag(Ks, tb * 16 + ln, kk * 32 + quad * 8);
                #pragma unroll
                for (int s = 0; s < 2; ++s)
                    #pragma unroll
                    for (int tb = 0; tb < 4; ++tb)
                        sc[s][tb] = __builtin_amdgcn_mfma_f32_16x16x32_bf16(kf[tb], qf[s][kk], sc[s][tb], 0, 0, 0);
            }

            #pragma unroll
            for (int s = 0; s < 2; ++s) {
                unsigned long long bm = bits[((size_t)b * SEQ + q0 + w * 32 + s * 16 + ln) * 16 + tt];
                if (__any(bm != ~0ull)) {
                    #pragma unroll
                    for (int tb = 0; tb < 4; ++tb)
                        #pragma unroll
                        for (int reg = 0; reg < 4; ++reg)
                            if (!((bm >> (tb * 16 + quad * 4 + reg)) & 1)) sc[s][tb][reg] = -1e30f;
                }
            }

            #pragma unroll
            for (int s = 0; s < 2; ++s) {
                int mrow = w * 32 + s * 16 + ln;
                #pragma unroll
                for (int tb = 0; tb < 4; ++tb) {
                    union { float f; unsigned int i; } e0_, e1_, e2_, e3_;
                    e0_.f = __builtin_amdgcn_exp2f(sc[s][tb][0]);
                    e1_.f = __builtin_amdgcn_exp2f(sc[s][tb][1]);
                    e2_.f = __builtin_amdgcn_exp2f(sc[s][tb][2]);
                    e3_.f = __builtin_amdgcn_exp2f(sc[s][tb][3]);
                    uint2 pk;
                    pk.x = ((e0_.i + 0x8000u) >> 16) | ((e1_.i + 0x8000u) & 0xFFFF0000u);
                    pk.y = ((e2_.i + 0x8000u) >> 16) | ((e3_.i + 0x8000u) & 0xFFFF0000u);
                    *(uint2*)&Ps[mrow * PP + tb * 16 + quad * 4] = pk;
                }
            }

            #pragma unroll
            for (int kk = 0; kk < 2; ++kk) {
                bf16x8 vf[5];
                #pragma unroll
                for (int dt = 0; dt < 5; ++dt)
                    vf[dt] = ldsfrag(Vs, dt * 16 + ln, kk * 32 + quad * 8);
                #pragma unroll
                for (int s = 0; s < 2; ++s) {
                    bf16x8 pf = s2b(*(const short8*)&Ps[(w * 32 + s * 16 + ln) * PP + kk * 32 + quad * 8]);
                    #pragma unroll
                    for (int dt = 0; dt < 5; ++dt)
                        o[s][dt] = __builtin_amdgcn_mfma_f32_16x16x32_bf16(pf, vf[dt], o[s][dt], 0, 0, 0);
                }
            }
        }

        #pragma unroll
        for (int s = 0; s < 2; ++s) {
            #pragma unroll
            for (int reg = 0; reg < 4; ++reg) {
                float l = __shfl(o[s][4][reg], lane & 48, 64);
                float inv = 1.0f / l;
                int m = q0 + w * 32 + s * 16 + quad * 4 + reg;
                #pragma unroll
                for (int dt = 0; dt < 4; ++dt)
                    Ao[((size_t)b * SEQ + m) * EMB + h * HD + dt * 16 + ln] = f2b_rn(o[s][dt][reg] * inv);
            }
        }
    }
    grid_sync(cnt, 3 * GRID);

    // ================= P3: out projection — 512 units (64x128 tiles) ========
    if (bid < 512) {
        u16* As = lds.p.As;
        u16* Bs = lds.p.Bs;
        int m0 = (bid & 63) * 64;
        int n0 = (bid >> 6) * 128;
        int wm = w & 1, wn = w >> 1;

        floatx4 acc[2][4] = {};

        for (int k0 = 0; k0 < EMB; k0 += 64) {
            __syncthreads();
            #pragma unroll
            for (int i = 0; i < 2; ++i) {
                int flat0 = i * 256 + (tid & 192);
                int flat = flat0 + lane;
                int r = flat >> 3;
                int c = ((flat & 7) ^ (r & 7)) * 8;
                gload_lds16(Ao + (size_t)(m0 + r) * EMB + k0 + c, As + flat0 * 8);
            }
            #pragma unroll
            for (int i = 0; i < 4; ++i) {
                int flat0 = i * 256 + (tid & 192);
                int flat = flat0 + lane;
                int r = flat >> 3;
                int c = ((flat & 7) ^ (r & 7)) * 8;
                gload_lds16(Wob + (size_t)(n0 + r) * EMB + k0 + c, Bs + flat0 * 8);
            }
            __syncthreads();

            #pragma unroll
            for (int kk = 0; kk < 2; ++kk) {
                bf16x8 a[2], bfr[4];
                #pragma unroll
                for (int mt = 0; mt < 2; ++mt)
                    a[mt] = ldsfrag(As, wm * 32 + mt * 16 + ln, kk * 32 + quad * 8);
                #pragma unroll
                for (int nc = 0; nc < 4; ++nc)
                    bfr[nc] = ldsfrag(Bs, wn * 64 + nc * 16 + ln, kk * 32 + quad * 8);
                #pragma unroll
                for (int mt = 0; mt < 2; ++mt)
                    #pragma unroll
                    for (int nc = 0; nc < 4; ++nc)
                        acc[mt][nc] = __builtin_amdgcn_mfma_f32_16x16x32_bf16(a[mt], bfr[nc], acc[mt][nc], 0, 0, 0);
            }
        }

        #pragma unroll
        for (int nc = 0; nc < 4; ++nc) {
            int n = n0 + wn * 64 + nc * 16 + ln;
            float bb = bo[n];
            #pragma unroll
            for (int mt = 0; mt < 2; ++mt) {
                #pragma unroll
                for (int reg = 0; reg < 4; ++reg) {
                    int m = m0 + wm * 32 + mt * 16 + quad * 4 + reg;
                    Out[(size_t)m * EMB + n] = acc[mt][nc][reg] + bb;
                }
            }
        }
    }
}

// ---------------------------------------------------------------------------
extern "C" void kernel_launch(void* const* d_in, const int* in_sizes, int n_in,
                              void* d_out, int out_size, void* d_ws, size_t ws_size,
                              hipStream_t stream) {
    const float* x  = (const float*)d_in[0];
    const int*   mk = (const int*)d_in[1];
    const float* Wq = (const float*)d_in[2];
    const float* bq = (const float*)d_in[3];
    const float* Wk = (const float*)d_in[4];
    const float* bk = (const float*)d_in[5];
    const float* Wv = (const float*)d_in[6];
    const float* bv = (const float*)d_in[7];
    const float* Wo = (const float*)d_in[8];
    const float* bo = (const float*)d_in[9];
    float* out = (float*)d_out;

    const size_t MB = 1u << 20;
    char* ws = (char*)d_ws;
    u16* xb  = (u16*)ws;                                   // [ 0, 8M)
    u16* Wt  = (u16*)(ws + 8 * MB);                        // [ 8,14M)
    u16* Wob = (u16*)(ws + 14 * MB);                       // [14,16M)
    unsigned long long* bits = (unsigned long long*)(ws + 16 * MB); // [16,16.5M)
    u16* Qw  = (u16*)(ws + 16 * MB + 512 * 1024);          // [16.5,24.5M)
    u16* Kw  = (u16*)(ws + 24 * MB + 512 * 1024);          // [24.5,32.5M)
    u16* Vtw = (u16*)(ws + 32 * MB + 512 * 1024);          // [32.5,40.5M)
    unsigned int* cnt = (unsigned int*)(ws + 41 * MB);     // barrier counter
    u16* Ao  = xb;                                         // reuse: xb dead after P1

    hipMemsetAsync(cnt, 0, 4, stream);
    fused_mha<<<GRID, 256, 0, stream>>>(
        x, mk, Wq, Wk, Wv, Wo, bq, bk, bv, bo,
        xb, Wt, Wob, bits, Qw, Kw, Vtw, Ao, out, cnt);
}

// Round 14
// 483.635 us; speedup vs baseline: 1.0054x; 1.0054x over previous
//
#include <hip/hip_runtime.h>
#include <hip/hip_bf16.h>

#define NB 4       // batch
#define SEQ 1024
#define EMB 1024
#define NH 16
#define HD 64
#define GRID 768   // persistent blocks; __launch_bounds__(256,3) guarantees 3/CU co-residency

typedef unsigned short u16;
typedef __attribute__((ext_vector_type(8))) __bf16 bf16x8;
typedef __attribute__((ext_vector_type(8))) short short8;
typedef __attribute__((ext_vector_type(4))) float floatx4;

__device__ inline u16 f2b_rn(float f) {
    union { float f; unsigned int i; } x; x.f = f;
    unsigned int r = (x.i + 0x7FFFu + ((x.i >> 16) & 1u)) >> 16;
    return (u16)r;
}
__device__ inline bf16x8 s2b(short8 v) {
    union { short8 s; bf16x8 b; } x; x.s = v; return x.b;
}
__device__ inline void gload_lds16(const void* g, void* l) {
    __builtin_amdgcn_global_load_lds(
        (const __attribute__((address_space(1))) void*)g,
        (__attribute__((address_space(3))) void*)l, 16, 0, 0);
}
// XOR-swizzled fragment read from an unpadded [rows][64] u16 LDS buffer.
__device__ inline bf16x8 ldsfrag(const u16* base, int r, int c) {
    return s2b(*(const short8*)&base[r * 64 + (c ^ ((r & 7) * 8))]);
}
__device__ inline void cvt8(const float* __restrict__ s, u16* __restrict__ d) {
    float4 a = *(const float4*)(s);
    float4 b = *(const float4*)(s + 4);
    union { u16 u[8]; int4 v; } o;
    o.u[0] = f2b_rn(a.x); o.u[1] = f2b_rn(a.y); o.u[2] = f2b_rn(a.z); o.u[3] = f2b_rn(a.w);
    o.u[4] = f2b_rn(b.x); o.u[5] = f2b_rn(b.y); o.u[6] = f2b_rn(b.z); o.u[7] = f2b_rn(b.w);
    *(int4*)(d) = o.v;
}

// device-scope grid barrier.  Arrive = atomicAdd (RMW, once per block).
// Poll = RELAXED DEVICE-SCOPE LOAD — r13's atomicAdd(cnt,0) poll was a full
// RMW: 768 pollers serialized at L2 and queued AHEAD of the arrive ops
// (~92 us/barrier).  Loads to one address broadcast and don't serialize.
__device__ inline void grid_sync(unsigned int* cnt, unsigned int target) {
    __syncthreads();
    if (threadIdx.x == 0) {
        __threadfence();                        // release
        atomicAdd(cnt, 1u);
        while (__hip_atomic_load(cnt, __ATOMIC_RELAXED, __HIP_MEMORY_SCOPE_AGENT) < target)
            __builtin_amdgcn_s_sleep(32);       // ~2k-cycle backoff
        __threadfence();                        // acquire
    }
    __syncthreads();
}

union SharedU {
    u16 T[64 * 80];                                              // P0 transpose: 10 KB
    struct { u16 As[128 * 64]; u16 Bs[128 * 64]; } g;            // P1 qkv: 32 KB
    struct { u16 Ks[64 * 64]; u16 Vs[80 * 64]; u16 Ps[128 * 72]; } a; // P2 attn: 36 KB
    struct { u16 As[64 * 64]; u16 Bs[128 * 64]; } p;             // P3 out_proj: 24 KB
};

// ---------------------------------------------------------------------------
// Single persistent kernel: 4 phases separated by grid barriers.
// ---------------------------------------------------------------------------
__global__ __launch_bounds__(256, 3) void fused_mha(
    const float* __restrict__ x, const int* __restrict__ mask,
    const float* __restrict__ Wq, const float* __restrict__ Wk, const float* __restrict__ Wv,
    const float* __restrict__ Wo,
    const float* __restrict__ bq, const float* __restrict__ bk, const float* __restrict__ bv,
    const float* __restrict__ bo,
    u16* __restrict__ xb, u16* __restrict__ Wt, u16* __restrict__ Wob,
    unsigned long long* __restrict__ bits,
    u16* __restrict__ Q, u16* __restrict__ K, u16* __restrict__ Vt,
    u16* __restrict__ Ao, float* __restrict__ Out,
    unsigned int* __restrict__ cnt)
{
    __shared__ SharedU lds;
    int bid = blockIdx.x;
    int tid = threadIdx.x;
    int lane = tid & 63, quad = lane >> 4, ln = lane & 15;
    int w = tid >> 6;

    // ================= P0: prep (x/Wo convert, W transpose, mask ballots) ===
    {
        // W transpose+convert: 768 units, 1 per block
        int e0 = (bid & 15) * 64;
        int ph = bid >> 4;              // 0..47
        int p = ph >> 4, h = ph & 15;
        const float* W = (p == 0 ? Wq : (p == 1 ? Wk : Wv)) + h * (EMB * HD);
        #pragma unroll
        for (int c = 0; c < 2; ++c) {
            int flat = c * 2048 + tid * 8;
            int r = flat >> 6;
            int d = flat & 63;
            cvt8(W + (size_t)(e0 + r) * HD + d, &lds.T[r * 80 + d]);
        }
        __syncthreads();
        int d = tid >> 2;
        int ec = tid & 3;
        union { u16 u[16]; int4 v[2]; } tmp;
        #pragma unroll
        for (int i = 0; i < 16; ++i) tmp.u[i] = lds.T[(ec * 16 + i) * 80 + d];
        u16* dst = Wt + ((size_t)(p * NH + h) * HD + d) * EMB + e0 + ec * 16;
        *(int4*)(dst) = tmp.v[0];
        *(int4*)(dst + 8) = tmp.v[1];

        // x fp32->bf16: 512 units x 4 chunks  +  Wo fp32->bf16: 512 units
        if (bid < 512) {
            #pragma unroll
            for (int c = 0; c < 4; ++c) {
                int i = (bid * 4 + c) * 2048 + tid * 8;
                cvt8(x + i, xb + i);
            }
            int i = bid * 2048 + tid * 8;
            cvt8(Wo + i, Wob + i);
        }
        // mask ballots: 4096 units x 16 rows (4 rows/wave)
        for (int u = bid; u < 4096; u += GRID) {
            int base = u * 16 + w * 4;
            #pragma unroll
            for (int i = 0; i < 4; ++i) {
                int gw = base + i;                    // 0..65535
                int m = mask[(size_t)gw * 64 + lane];
                unsigned long long bl = __ballot(m != 0);
                if (lane == 0) bits[gw] = bl;
            }
        }
    }
    grid_sync(cnt, GRID);

    // ================= P1: QKV GEMM — exactly 768 tiles, 1 per block ========
    {
        u16* As = lds.g.As;
        u16* Bs = lds.g.Bs;
        int n0 = (bid % 24) * 128;
        int m0 = (bid / 24) * 128;
        int wm = w & 1, wn = w >> 1;

        floatx4 acc[4][4] = {};

        for (int k0 = 0; k0 < EMB; k0 += 64) {
            __syncthreads();
            #pragma unroll
            for (int i = 0; i < 4; ++i) {
                int flat0 = i * 256 + (tid & 192);
                int flat = flat0 + lane;
                int r = flat >> 3;
                int c = ((flat & 7) ^ (r & 7)) * 8;
                gload_lds16(xb + (size_t)(m0 + r) * EMB + k0 + c, As + flat0 * 8);
                gload_lds16(Wt + (size_t)(n0 + r) * EMB + k0 + c, Bs + flat0 * 8);
            }
            __syncthreads();

            #pragma unroll
            for (int kk = 0; kk < 2; ++kk) {
                bf16x8 a[4], bf[4];
                #pragma unroll
                for (int mt = 0; mt < 4; ++mt)
                    a[mt] = ldsfrag(As, wm * 64 + mt * 16 + ln, kk * 32 + quad * 8);
                #pragma unroll
                for (int nc = 0; nc < 4; ++nc)
                    bf[nc] = ldsfrag(Bs, wn * 64 + nc * 16 + ln, kk * 32 + quad * 8);
                #pragma unroll
                for (int mt = 0; mt < 4; ++mt)
                    #pragma unroll
                    for (int nc = 0; nc < 4; ++nc)
                        acc[mt][nc] = __builtin_amdgcn_mfma_f32_16x16x32_bf16(a[mt], bf[nc], acc[mt][nc], 0, 0, 0);
            }
        }

        int p = n0 >> 10;
        const float* bias = (p == 0 ? bq : (p == 1 ? bk : bv));
        if (p < 2) {
            u16* Outp = (p == 0) ? Q : K;
            float qs = (p == 0) ? 0.125f * 1.44269504f : 1.0f;  // 1/sqrt(64) * log2(e)
            #pragma unroll
            for (int nc = 0; nc < 4; ++nc) {
                int n = n0 + wn * 64 + nc * 16 + ln;
                int h = (n >> 6) & 15, d = n & 63;
                float bv_ = bias[n & 1023];
                #pragma unroll
                for (int mt = 0; mt < 4; ++mt) {
                    #pragma unroll
                    for (int reg = 0; reg < 4; ++reg) {
                        int m = m0 + wm * 64 + mt * 16 + quad * 4 + reg;
                        int b_ = m >> 10, s = m & 1023;
                        Outp[((size_t)(b_ * NH + h) * SEQ + s) * HD + d] = f2b_rn((acc[mt][nc][reg] + bv_) * qs);
                    }
                }
            }
        } else {
            #pragma unroll
            for (int nc = 0; nc < 4; ++nc) {
                int n = n0 + wn * 64 + nc * 16 + ln;
                int h = (n >> 6) & 15, d = n & 63;
                float bv_ = bias[n & 1023];
                #pragma unroll
                for (int mt = 0; mt < 4; ++mt) {
                    int m = m0 + wm * 64 + mt * 16 + quad * 4;
                    int b_ = m >> 10, s = m & 1023;
                    union { u16 u[4]; uint2 v; } pk;
                    #pragma unroll
                    for (int reg = 0; reg < 4; ++reg)
                        pk.u[reg] = f2b_rn(acc[mt][nc][reg] + bv_);
                    *(uint2*)&Vt[((size_t)(b_ * NH + h) * HD + d) * SEQ + s] = pk.v;
                }
            }
        }
    }
    grid_sync(cnt, 2 * GRID);

    // ================= P2: attention — 512 units (bh, 128-row q-tile) =======
    if (bid < 512) {
        u16* Ks = lds.a.Ks;
        u16* Vs = lds.a.Vs;
        u16* Ps = lds.a.Ps;
        const int PP = 72;

        int bh = bid & 63;
        int q0 = (bid >> 6) * 128;
        int b = bh >> 4, h = bh & 15;
        const u16* Qb = Q  + (size_t)bh * SEQ * HD;
        const u16* Kb = K  + (size_t)bh * SEQ * HD;
        const u16* Vb = Vt + (size_t)bh * HD * SEQ;   // [d][s]

        if (tid < 16) *(uint2*)&Vs[64 * 64 + tid * 4] = make_uint2(0x3F803F80u, 0x3F803F80u);

        bf16x8 qf[2][2];
        #pragma unroll
        for (int s = 0; s < 2; ++s) {
            const u16* qp = Qb + (size_t)(q0 + w * 32 + s * 16 + ln) * HD + quad * 8;
            union { int4 i; bf16x8 b; } c0, c1;
            c0.i = *(const int4*)(qp);
            c1.i = *(const int4*)(qp + 32);
            qf[s][0] = c0.b; qf[s][1] = c1.b;
        }

        floatx4 o[2][5] = {};

        for (int tt = 0; tt < SEQ / 64; ++tt) {
            int t0 = tt * 64;
            __syncthreads();
            #pragma unroll
            for (int i = 0; i < 2; ++i) {
                int flat0 = i * 256 + (tid & 192);
                int flat = flat0 + lane;
                int r = flat >> 3;
                int c = ((flat & 7) ^ (r & 7)) * 8;
                gload_lds16(Kb + (size_t)(t0 + r) * HD + c, Ks + flat0 * 8);
                gload_lds16(Vb + (size_t)r * SEQ + t0 + c, Vs + flat0 * 8);
            }
            __syncthreads();

            floatx4 sc[2][4] = {};
            #pragma unroll
            for (int kk = 0; kk < 2; ++kk) {
                bf16x8 kf[4];
                #pragma unroll
                for (int tb = 0; tb < 4; ++tb)
                    kf[tb] = ldsfrag(Ks, tb * 16 + ln, kk * 32 + quad * 8);
                #pragma unroll
                for (int s = 0; s < 2; ++s)
                    #pragma unroll
                    for (int tb = 0; tb < 4; ++tb)
                        sc[s][tb] = __builtin_amdgcn_mfma_f32_16x16x32_bf16(kf[tb], qf[s][kk], sc[s][tb], 0, 0, 0);
            }

            #pragma unroll
            for (int s = 0; s < 2; ++s) {
                unsigned long long bm = bits[((size_t)b * SEQ + q0 + w * 32 + s * 16 + ln) * 16 + tt];
                if (__any(bm != ~0ull)) {
                    #pragma unroll
                    for (int tb = 0; tb < 4; ++tb)
                        #pragma unroll
                        for (int reg = 0; reg < 4; ++reg)
                            if (!((bm >> (tb * 16 + quad * 4 + reg)) & 1)) sc[s][tb][reg] = -1e30f;
                }
            }

            #pragma unroll
            for (int s = 0; s < 2; ++s) {
                int mrow = w * 32 + s * 16 + ln;
                #pragma unroll
                for (int tb = 0; tb < 4; ++tb) {
                    union { float f; unsigned int i; } e0_, e1_, e2_, e3_;
                    e0_.f = __builtin_amdgcn_exp2f(sc[s][tb][0]);
                    e1_.f = __builtin_amdgcn_exp2f(sc[s][tb][1]);
                    e2_.f = __builtin_amdgcn_exp2f(sc[s][tb][2]);
                    e3_.f = __builtin_amdgcn_exp2f(sc[s][tb][3]);
                    uint2 pk;
                    pk.x = ((e0_.i + 0x8000u) >> 16) | ((e1_.i + 0x8000u) & 0xFFFF0000u);
                    pk.y = ((e2_.i + 0x8000u) >> 16) | ((e3_.i + 0x8000u) & 0xFFFF0000u);
                    *(uint2*)&Ps[mrow * PP + tb * 16 + quad * 4] = pk;
                }
            }

            #pragma unroll
            for (int kk = 0; kk < 2; ++kk) {
                bf16x8 vf[5];
                #pragma unroll
                for (int dt = 0; dt < 5; ++dt)
                    vf[dt] = ldsfrag(Vs, dt * 16 + ln, kk * 32 + quad * 8);
                #pragma unroll
                for (int s = 0; s < 2; ++s) {
                    bf16x8 pf = s2b(*(const short8*)&Ps[(w * 32 + s * 16 + ln) * PP + kk * 32 + quad * 8]);
                    #pragma unroll
                    for (int dt = 0; dt < 5; ++dt)
                        o[s][dt] = __builtin_amdgcn_mfma_f32_16x16x32_bf16(pf, vf[dt], o[s][dt], 0, 0, 0);
                }
            }
        }

        #pragma unroll
        for (int s = 0; s < 2; ++s) {
            #pragma unroll
            for (int reg = 0; reg < 4; ++reg) {
                float l = __shfl(o[s][4][reg], lane & 48, 64);
                float inv = 1.0f / l;
                int m = q0 + w * 32 + s * 16 + quad * 4 + reg;
                #pragma unroll
                for (int dt = 0; dt < 4; ++dt)
                    Ao[((size_t)b * SEQ + m) * EMB + h * HD + dt * 16 + ln] = f2b_rn(o[s][dt][reg] * inv);
            }
        }
    }
    grid_sync(cnt, 3 * GRID);

    // ================= P3: out projection — 512 units (64x128 tiles) ========
    if (bid < 512) {
        u16* As = lds.p.As;
        u16* Bs = lds.p.Bs;
        int m0 = (bid & 63) * 64;
        int n0 = (bid >> 6) * 128;
        int wm = w & 1, wn = w >> 1;

        floatx4 acc[2][4] = {};

        for (int k0 = 0; k0 < EMB; k0 += 64) {
            __syncthreads();
            #pragma unroll
            for (int i = 0; i < 2; ++i) {
                int flat0 = i * 256 + (tid & 192);
                int flat = flat0 + lane;
                int r = flat >> 3;
                int c = ((flat & 7) ^ (r & 7)) * 8;
                gload_lds16(Ao + (size_t)(m0 + r) * EMB + k0 + c, As + flat0 * 8);
            }
            #pragma unroll
            for (int i = 0; i < 4; ++i) {
                int flat0 = i * 256 + (tid & 192);
                int flat = flat0 + lane;
                int r = flat >> 3;
                int c = ((flat & 7) ^ (r & 7)) * 8;
                gload_lds16(Wob + (size_t)(n0 + r) * EMB + k0 + c, Bs + flat0 * 8);
            }
            __syncthreads();

            #pragma unroll
            for (int kk = 0; kk < 2; ++kk) {
                bf16x8 a[2], bfr[4];
                #pragma unroll
                for (int mt = 0; mt < 2; ++mt)
                    a[mt] = ldsfrag(As, wm * 32 + mt * 16 + ln, kk * 32 + quad * 8);
                #pragma unroll
                for (int nc = 0; nc < 4; ++nc)
                    bfr[nc] = ldsfrag(Bs, wn * 64 + nc * 16 + ln, kk * 32 + quad * 8);
                #pragma unroll
                for (int mt = 0; mt < 2; ++mt)
                    #pragma unroll
                    for (int nc = 0; nc < 4; ++nc)
                        acc[mt][nc] = __builtin_amdgcn_mfma_f32_16x16x32_bf16(a[mt], bfr[nc], acc[mt][nc], 0, 0, 0);
            }
        }

        #pragma unroll
        for (int nc = 0; nc < 4; ++nc) {
            int n = n0 + wn * 64 + nc * 16 + ln;
            float bb = bo[n];
            #pragma unroll
            for (int mt = 0; mt < 2; ++mt) {
                #pragma unroll
                for (int reg = 0; reg < 4; ++reg) {
                    int m = m0 + wm * 32 + mt * 16 + quad * 4 + reg;
                    Out[(size_t)m * EMB + n] = acc[mt][nc][reg] + bb;
                }
            }
        }
    }
}

// ---------------------------------------------------------------------------
extern "C" void kernel_launch(void* const* d_in, const int* in_sizes, int n_in,
                              void* d_out, int out_size, void* d_ws, size_t ws_size,
                              hipStream_t stream) {
    const float* x  = (const float*)d_in[0];
    const int*   mk = (const int*)d_in[1];
    const float* Wq = (const float*)d_in[2];
    const float* bq = (const float*)d_in[3];
    const float* Wk = (const float*)d_in[4];
    const float* bk = (const float*)d_in[5];
    const float* Wv = (const float*)d_in[6];
    const float* bv = (const float*)d_in[7];
    const float* Wo = (const float*)d_in[8];
    const float* bo = (const float*)d_in[9];
    float* out = (float*)d_out;

    const size_t MB = 1u << 20;
    char* ws = (char*)d_ws;
    u16* xb  = (u16*)ws;                                   // [ 0, 8M)
    u16* Wt  = (u16*)(ws + 8 * MB);                        // [ 8,14M)
    u16* Wob = (u16*)(ws + 14 * MB);                       // [14,16M)
    unsigned long long* bits = (unsigned long long*)(ws + 16 * MB); // [16,16.5M)
    u16* Qw  = (u16*)(ws + 16 * MB + 512 * 1024);          // [16.5,24.5M)
    u16* Kw  = (u16*)(ws + 24 * MB + 512 * 1024);          // [24.5,32.5M)
    u16* Vtw = (u16*)(ws + 32 * MB + 512 * 1024);          // [32.5,40.5M)
    unsigned int* cnt = (unsigned int*)(ws + 41 * MB);     // barrier counter
    u16* Ao  = xb;                                         // reuse: xb dead after P1

    hipMemsetAsync(cnt, 0, 4, stream);
    fused_mha<<<GRID, 256, 0, stream>>>(
        x, mk, Wq, Wk, Wv, Wo, bq, bk, bv, bo,
        xb, Wt, Wob, bits, Qw, Kw, Vtw, Ao, out, cnt);
}

// Round 15
// 198.652 us; speedup vs baseline: 2.4478x; 2.4346x over previous
//
#include <hip/hip_runtime.h>
#include <hip/hip_bf16.h>

#define NB 4       // batch
#define SEQ 1024
#define EMB 1024
#define NH 16
#define HD 64

typedef unsigned short u16;
typedef __attribute__((ext_vector_type(8))) __bf16 bf16x8;
typedef __attribute__((ext_vector_type(8))) short short8;
typedef __attribute__((ext_vector_type(4))) float floatx4;

// fp32 -> bf16 round-to-nearest-even
__device__ inline u16 f2b_rn(float f) {
    union { float f; unsigned int i; } x; x.f = f;
    unsigned int r = (x.i + 0x7FFFu + ((x.i >> 16) & 1u)) >> 16;
    return (u16)r;
}
__device__ inline bf16x8 s2b(short8 v) {
    union { short8 s; bf16x8 b; } x; x.s = v; return x.b;
}

// async global->LDS, 16 B per lane.  LDS dest = wave-uniform base + lane*16.
__device__ inline void gload_lds16(const void* g, void* l) {
    __builtin_amdgcn_global_load_lds(
        (const __attribute__((address_space(1))) void*)g,
        (__attribute__((address_space(3))) void*)l, 16, 0, 0);
}

// XOR-swizzled fragment read from an unpadded [rows][64] u16 LDS buffer.
// One row = 128 B = all 32 banks; (r&7) XOR spreads 16-lane b128 reads.
__device__ inline bf16x8 ldsfrag(const u16* base, int r, int c) {
    return s2b(*(const short8*)&base[r * 64 + (c ^ ((r & 7) * 8))]);
}

__device__ inline void cvt8(const float* __restrict__ s, u16* __restrict__ d) {
    float4 a = *(const float4*)(s);
    float4 b = *(const float4*)(s + 4);
    union { u16 u[8]; int4 v; } o;
    o.u[0] = f2b_rn(a.x); o.u[1] = f2b_rn(a.y); o.u[2] = f2b_rn(a.z); o.u[3] = f2b_rn(a.w);
    o.u[4] = f2b_rn(b.x); o.u[5] = f2b_rn(b.y); o.u[6] = f2b_rn(b.z); o.u[7] = f2b_rn(b.w);
    *(int4*)(d) = o.v;
}

// ---------------------------------------------------------------------------
// Kernel P: prep.  blockIdx.x ranges:
//   [0,512)      x fp32->bf16   (4 x 2048 elems per block)
//   [512,1280)   W transpose+convert -> Wt[3072][1024]
//   [1280,5376)  mask -> bitmask (4096 blocks x 16 rows; 4 rows/wave)
// ---------------------------------------------------------------------------
__global__ __launch_bounds__(256) void prep(
    const float* __restrict__ x, const float* __restrict__ Wq,
    const float* __restrict__ Wk, const float* __restrict__ Wv,
    const int* __restrict__ mask,
    u16* __restrict__ xb, u16* __restrict__ Wt,
    unsigned long long* __restrict__ bits)
{
    __shared__ u16 T[64 * 80];
    int bx = blockIdx.x;
    int tid = threadIdx.x;

    if (bx < 512) {
        #pragma unroll
        for (int c = 0; c < 4; ++c) {
            int i = (bx * 4 + c) * 2048 + tid * 8;
            cvt8(x + i, xb + i);
        }
    } else if (bx < 1280) {
        int bx2 = bx - 512;
        int e0 = (bx2 & 15) * 64;
        int ph = bx2 >> 4;              // 0..47
        int p = ph >> 4, h = ph & 15;
        const float* W = (p == 0 ? Wq : (p == 1 ? Wk : Wv)) + h * (EMB * HD);
        #pragma unroll
        for (int c = 0; c < 2; ++c) {
            int flat = c * 2048 + tid * 8;
            int r = flat >> 6;
            int d = flat & 63;
            cvt8(W + (size_t)(e0 + r) * HD + d, &T[r * 80 + d]);
        }
        __syncthreads();
        int d = tid >> 2;
        int ec = tid & 3;
        union { u16 u[16]; int4 v[2]; } tmp;
        #pragma unroll
        for (int i = 0; i < 16; ++i) tmp.u[i] = T[(ec * 16 + i) * 80 + d];
        u16* dst = Wt + ((size_t)(p * NH + h) * HD + d) * EMB + e0 + ec * 16;
        *(int4*)(dst) = tmp.v[0];
        *(int4*)(dst + 8) = tmp.v[1];
    } else {
        int base = (bx - 1280) * 16 + (tid >> 6) * 4;    // 4 waves x 4 rows
        int lane = tid & 63;
        #pragma unroll
        for (int i = 0; i < 4; ++i) {
            int gw = base + i;                            // 0..65535
            int m = mask[(size_t)gw * 64 + lane];
            unsigned long long bl = __ballot(m != 0);
            if (lane == 0) bits[gw] = bl;
        }
    }
}

// ---------------------------------------------------------------------------
// Kernel 1: PURE fused QKV GEMM, m97 recipe (measured 48 us / 537 TF).
// Grid 768: n0=(gid%24)*128, m0=(gid/24)*128 (same-n blocks at id-stride 24
// == 0 mod 8 -> same XCD).  C[4096][3072] = x @ Wt^T (+bias); BK=64.
// Q scaled by log2(e)/8; V written transposed Vt[b,h][d][s].
// ---------------------------------------------------------------------------
__global__ __launch_bounds__(256) void qkv_gemm(
    const u16* __restrict__ x,    // bf16 [4096][1024]
    const u16* __restrict__ Wt2,  // bf16 [3072][1024]
    const float* __restrict__ bq, const float* __restrict__ bk, const float* __restrict__ bv,
    u16* __restrict__ Q, u16* __restrict__ K, u16* __restrict__ Vt)
{
    __shared__ u16 As[128 * 64];
    __shared__ u16 Bs[128 * 64];

    int gid = blockIdx.x;
    int n0 = (gid % 24) * 128;
    int m0 = (gid / 24) * 128;
    int tid = threadIdx.x;
    int w = tid >> 6, lane = tid & 63, quad = lane >> 4, ln = lane & 15;
    int wm = w & 1, wn = w >> 1;

    floatx4 acc[4][4] = {};

    for (int k0 = 0; k0 < EMB; k0 += 64) {
        __syncthreads();
        #pragma unroll
        for (int i = 0; i < 4; ++i) {
            int flat0 = i * 256 + (tid & 192);
            int flat = flat0 + lane;
            int r = flat >> 3;
            int c = ((flat & 7) ^ (r & 7)) * 8;
            gload_lds16(x   + (size_t)(m0 + r) * EMB + k0 + c, As + flat0 * 8);
            gload_lds16(Wt2 + (size_t)(n0 + r) * EMB + k0 + c, Bs + flat0 * 8);
        }
        __syncthreads();

        #pragma unroll
        for (int kk = 0; kk < 2; ++kk) {
            bf16x8 a[4], bf[4];
            #pragma unroll
            for (int mt = 0; mt < 4; ++mt)
                a[mt] = ldsfrag(As, wm * 64 + mt * 16 + ln, kk * 32 + quad * 8);
            #pragma unroll
            for (int nc = 0; nc < 4; ++nc)
                bf[nc] = ldsfrag(Bs, wn * 64 + nc * 16 + ln, kk * 32 + quad * 8);
            #pragma unroll
            for (int mt = 0; mt < 4; ++mt)
                #pragma unroll
                for (int nc = 0; nc < 4; ++nc)
                    acc[mt][nc] = __builtin_amdgcn_mfma_f32_16x16x32_bf16(a[mt], bf[nc], acc[mt][nc], 0, 0, 0);
        }
    }

    int p = n0 >> 10;
    const float* bias = (p == 0 ? bq : (p == 1 ? bk : bv));
    if (p < 2) {
        u16* Out = (p == 0) ? Q : K;
        float qs = (p == 0) ? 0.125f * 1.44269504f : 1.0f;   // fold 1/sqrt(64) and log2(e)
        #pragma unroll
        for (int nc = 0; nc < 4; ++nc) {
            int n = n0 + wn * 64 + nc * 16 + ln;
            int h = (n >> 6) & 15, d = n & 63;
            float bv_ = bias[n & 1023];
            #pragma unroll
            for (int mt = 0; mt < 4; ++mt) {
                #pragma unroll
                for (int reg = 0; reg < 4; ++reg) {
                    int m = m0 + wm * 64 + mt * 16 + quad * 4 + reg;
                    int b_ = m >> 10, s = m & 1023;
                    Out[((size_t)(b_ * NH + h) * SEQ + s) * HD + d] = f2b_rn((acc[mt][nc][reg] + bv_) * qs);
                }
            }
        }
    } else {
        #pragma unroll
        for (int nc = 0; nc < 4; ++nc) {
            int n = n0 + wn * 64 + nc * 16 + ln;
            int h = (n >> 6) & 15, d = n & 63;
            float bv_ = bias[n & 1023];
            #pragma unroll
            for (int mt = 0; mt < 4; ++mt) {
                int m = m0 + wm * 64 + mt * 16 + quad * 4;
                int b_ = m >> 10, s = m & 1023;
                union { u16 u[4]; uint2 v; } pk;
                #pragma unroll
                for (int reg = 0; reg < 4; ++reg)
                    pk.u[reg] = f2b_rn(acc[mt][nc][reg] + bv_);
                *(uint2*)&Vt[((size_t)(b_ * NH + h) * HD + d) * SEQ + s] = pk.v;
            }
        }
    }
}

// ---------------------------------------------------------------------------
// Kernel 2: flash attention v3 + Wo-convert tail blocks.  1D grid, 128 thr:
//   bid < 1024 : attn unit; bh = bid & 63 (same-(b,h) at stride 64 -> same
//                XCD), q0 = (bid >> 6) * 64.
//   bid >= 1024: Wo fp32->bf16 tail (1024 blocks x 1024 elems) — Wob is
//                consumed only by out_proj (a later dispatch), so these ride
//                in attn's occupancy shadow.
// S^T = K Q^T: lane owns one softmax column; P = exp2 (Q carries log2e/8);
// l from a ones-row appended to V.
// ---------------------------------------------------------------------------
__global__ __launch_bounds__(128) void attn(
    const u16* __restrict__ Q, const u16* __restrict__ K, const u16* __restrict__ Vt,
    const unsigned long long* __restrict__ bits,
    const float* __restrict__ Wo, u16* __restrict__ Wob,
    u16* __restrict__ Aout)         // bf16 [B][S][E]
{
    const int PP = 72;  // Ps row stride in u16 (144 B)
    __shared__ u16 Ks[64 * 64];
    __shared__ u16 Vs[80 * 64];     // rows 0..63 = V^T tile, row 64 = ones
    __shared__ u16 Ps[64 * PP];

    int bid = blockIdx.x;
    int tid = threadIdx.x;

    if (bid >= 1024) {               // Wo convert tail
        int i = (bid - 1024) * 1024 + tid * 8;
        cvt8(Wo + i, Wob + i);
        return;
    }

    int bh = bid & 63;
    int q0 = (bid >> 6) * 64;
    int b = bh >> 4, h = bh & 15;
    const u16* Qb = Q  + (size_t)bh * SEQ * HD;
    const u16* Kb = K  + (size_t)bh * SEQ * HD;
    const u16* Vb = Vt + (size_t)bh * HD * SEQ;   // [d][s]

    int w = tid >> 6, lane = tid & 63, quad = lane >> 4, ln = lane & 15;

    if (tid < 16) *(uint2*)&Vs[64 * 64 + tid * 4] = make_uint2(0x3F803F80u, 0x3F803F80u);

    bf16x8 qf[2][2];
    #pragma unroll
    for (int s = 0; s < 2; ++s) {
        const u16* qp = Qb + (size_t)(q0 + w * 32 + s * 16 + ln) * HD + quad * 8;
        union { int4 i; bf16x8 b; } c0, c1;
        c0.i = *(const int4*)(qp);
        c1.i = *(const int4*)(qp + 32);
        qf[s][0] = c0.b; qf[s][1] = c1.b;
    }

    floatx4 o[2][5] = {};   // [strip][dt], dt=4 is the l column

    for (int tt = 0; tt < SEQ / 64; ++tt) {
        int t0 = tt * 64;
        __syncthreads();
        #pragma unroll
        for (int i = 0; i < 4; ++i) {
            int flat0 = i * 128 + (tid & 64);
            int flat = flat0 + lane;
            int r = flat >> 3;
            int c = ((flat & 7) ^ (r & 7)) * 8;
            gload_lds16(Kb + (size_t)(t0 + r) * HD + c, Ks + flat0 * 8);
            gload_lds16(Vb + (size_t)r * SEQ + t0 + c, Vs + flat0 * 8);
        }
        __syncthreads();

        // S^T = K Q^T : rows t, cols m
        floatx4 sc[2][4] = {};
        #pragma unroll
        for (int kk = 0; kk < 2; ++kk) {
            bf16x8 kf[4];
            #pragma unroll
            for (int tb = 0; tb < 4; ++tb)
                kf[tb] = ldsfrag(Ks, tb * 16 + ln, kk * 32 + quad * 8);
            #pragma unroll
            for (int s = 0; s < 2; ++s)
                #pragma unroll
                for (int tb = 0; tb < 4; ++tb)
                    sc[s][tb] = __builtin_amdgcn_mfma_f32_16x16x32_bf16(kf[tb], qf[s][kk], sc[s][tb], 0, 0, 0);
        }

        #pragma unroll
        for (int s = 0; s < 2; ++s) {
            unsigned long long bm = bits[((size_t)b * SEQ + q0 + w * 32 + s * 16 + ln) * 16 + tt];
            if (__any(bm != ~0ull)) {
                #pragma unroll
                for (int tb = 0; tb < 4; ++tb)
                    #pragma unroll
                    for (int reg = 0; reg < 4; ++reg)
                        if (!((bm >> (tb * 16 + quad * 4 + reg)) & 1)) sc[s][tb][reg] = -1e30f;
            }
        }

        // P = exp2(S), pack 4 consecutive t -> b64 LDS write
        #pragma unroll
        for (int s = 0; s < 2; ++s) {
            int mrow = w * 32 + s * 16 + ln;
            #pragma unroll
            for (int tb = 0; tb < 4; ++tb) {
                union { float f; unsigned int i; } e0_, e1_, e2_, e3_;
                e0_.f = __builtin_amdgcn_exp2f(sc[s][tb][0]);
                e1_.f = __builtin_amdgcn_exp2f(sc[s][tb][1]);
                e2_.f = __builtin_amdgcn_exp2f(sc[s][tb][2]);
                e3_.f = __builtin_amdgcn_exp2f(sc[s][tb][3]);
                uint2 pk;
                pk.x = ((e0_.i + 0x8000u) >> 16) | ((e1_.i + 0x8000u) & 0xFFFF0000u);
                pk.y = ((e2_.i + 0x8000u) >> 16) | ((e3_.i + 0x8000u) & 0xFFFF0000u);
                *(uint2*)&Ps[mrow * PP + tb * 16 + quad * 4] = pk;
            }
        }

        // O += P V  (l accumulates in dt=4 via the ones row)
        #pragma unroll
        for (int kk = 0; kk < 2; ++kk) {
            bf16x8 vf[5];
            #pragma unroll
            for (int dt = 0; dt < 5; ++dt)
                vf[dt] = ldsfrag(Vs, dt * 16 + ln, kk * 32 + quad * 8);
            #pragma unroll
            for (int s = 0; s < 2; ++s) {
                bf16x8 pf = s2b(*(const short8*)&Ps[(w * 32 + s * 16 + ln) * PP + kk * 32 + quad * 8]);
                #pragma unroll
                for (int dt = 0; dt < 5; ++dt)
                    o[s][dt] = __builtin_amdgcn_mfma_f32_16x16x32_bf16(pf, vf[dt], o[s][dt], 0, 0, 0);
            }
        }
    }

    #pragma unroll
    for (int s = 0; s < 2; ++s) {
        #pragma unroll
        for (int reg = 0; reg < 4; ++reg) {
            float l = __shfl(o[s][4][reg], lane & 48, 64);
            float inv = 1.0f / l;
            int m = q0 + w * 32 + s * 16 + quad * 4 + reg;
            #pragma unroll
            for (int dt = 0; dt < 4; ++dt)
                Aout[((size_t)b * SEQ + m) * EMB + h * HD + dt * 16 + ln] = f2b_rn(o[s][dt][reg] * inv);
        }
    }
}

// ---------------------------------------------------------------------------
// Kernel 3: output projection.  64x128 tile, BK=64 single buffer, grid 512
// (2 blocks/CU).  Out[4096][1024] fp32.
// ---------------------------------------------------------------------------
__global__ __launch_bounds__(256) void out_proj(
    const u16* __restrict__ A,    // bf16 [4096][1024]
    const u16* __restrict__ Wo,   // bf16 [1024][1024] (n,k)
    const float* __restrict__ bo,
    float* __restrict__ Out)
{
    __shared__ u16 As[64 * 64];
    __shared__ u16 Bs[128 * 64];

    int m0 = blockIdx.x * 64;
    int n0 = blockIdx.y * 128;
    int tid = threadIdx.x;
    int w = tid >> 6, lane = tid & 63, quad = lane >> 4, ln = lane & 15;
    int wm = w & 1, wn = w >> 1;

    floatx4 acc[2][4] = {};

    for (int k0 = 0; k0 < EMB; k0 += 64) {
        __syncthreads();
        #pragma unroll
        for (int i = 0; i < 2; ++i) {
            int flat0 = i * 256 + (tid & 192);
            int flat = flat0 + lane;
            int r = flat >> 3;                   // 0..63
            int c = ((flat & 7) ^ (r & 7)) * 8;
            gload_lds16(A + (size_t)(m0 + r) * EMB + k0 + c, As + flat0 * 8);
        }
        #pragma unroll
        for (int i = 0; i < 4; ++i) {
            int flat0 = i * 256 + (tid & 192);
            int flat = flat0 + lane;
            int r = flat >> 3;                   // 0..127
            int c = ((flat & 7) ^ (r & 7)) * 8;
            gload_lds16(Wo + (size_t)(n0 + r) * EMB + k0 + c, Bs + flat0 * 8);
        }
        __syncthreads();

        #pragma unroll
        for (int kk = 0; kk < 2; ++kk) {
            bf16x8 a[2], bfr[4];
            #pragma unroll
            for (int mt = 0; mt < 2; ++mt)
                a[mt] = ldsfrag(As, wm * 32 + mt * 16 + ln, kk * 32 + quad * 8);
            #pragma unroll
            for (int nc = 0; nc < 4; ++nc)
                bfr[nc] = ldsfrag(Bs, wn * 64 + nc * 16 + ln, kk * 32 + quad * 8);
            #pragma unroll
            for (int mt = 0; mt < 2; ++mt)
                #pragma unroll
                for (int nc = 0; nc < 4; ++nc)
                    acc[mt][nc] = __builtin_amdgcn_mfma_f32_16x16x32_bf16(a[mt], bfr[nc], acc[mt][nc], 0, 0, 0);
        }
    }

    #pragma unroll
    for (int nc = 0; nc < 4; ++nc) {
        int n = n0 + wn * 64 + nc * 16 + ln;
        float bb = bo[n];
        #pragma unroll
        for (int mt = 0; mt < 2; ++mt) {
            #pragma unroll
            for (int reg = 0; reg < 4; ++reg) {
                int m = m0 + wm * 32 + mt * 16 + quad * 4 + reg;
                Out[(size_t)m * EMB + n] = acc[mt][nc][reg] + bb;
            }
        }
    }
}

// ---------------------------------------------------------------------------
extern "C" void kernel_launch(void* const* d_in, const int* in_sizes, int n_in,
                              void* d_out, int out_size, void* d_ws, size_t ws_size,
                              hipStream_t stream) {
    const float* x  = (const float*)d_in[0];
    const int*   mk = (const int*)d_in[1];
    const float* Wq = (const float*)d_in[2];
    const float* bq = (const float*)d_in[3];
    const float* Wk = (const float*)d_in[4];
    const float* bk = (const float*)d_in[5];
    const float* Wv = (const float*)d_in[6];
    const float* bv = (const float*)d_in[7];
    const float* Wo = (const float*)d_in[8];
    const float* bo = (const float*)d_in[9];
    float* out = (float*)d_out;

    const size_t MB = 1u << 20;
    char* ws = (char*)d_ws;
    u16* xb  = (u16*)ws;                                   // [ 0, 8M)
    u16* Wt  = (u16*)(ws + 8 * MB);                        // [ 8,14M)
    u16* Wob = (u16*)(ws + 14 * MB);                       // [14,16M)
    unsigned long long* bits = (unsigned long long*)(ws + 16 * MB); // [16,16.5M)
    u16* Qw  = (u16*)(ws + 16 * MB + 512 * 1024);          // [16.5,24.5M)
    u16* Kw  = (u16*)(ws + 24 * MB + 512 * 1024);          // [24.5,32.5M)
    u16* Vtw = (u16*)(ws + 32 * MB + 512 * 1024);          // [32.5,40.5M)
    u16* Ao  = xb;                                         // reuse: xb dead after qkv

    prep<<<5376, 256, 0, stream>>>(x, Wq, Wk, Wv, mk, xb, Wt, bits);
    qkv_gemm<<<768, 256, 0, stream>>>(xb, Wt, bq, bk, bv, Qw, Kw, Vtw);
    attn<<<2048, 128, 0, stream>>>(Qw, Kw, Vtw, bits, Wo, Wob, Ao);
    out_proj<<<dim3((NB * SEQ) / 64, EMB / 128), 256, 0, stream>>>(Ao, Wob, bo, out);
}

// Round 16
// 194.326 us; speedup vs baseline: 2.5023x; 1.0223x over previous
//
#include <hip/hip_runtime.h>
#include <hip/hip_bf16.h>

#define NB 4       // batch
#define SEQ 1024
#define EMB 1024
#define NH 16
#define HD 64

typedef unsigned short u16;
typedef __attribute__((ext_vector_type(8))) __bf16 bf16x8;
typedef __attribute__((ext_vector_type(8))) short short8;
typedef __attribute__((ext_vector_type(4))) float floatx4;

// fp32 -> bf16 round-to-nearest-even
__device__ inline u16 f2b_rn(float f) {
    union { float f; unsigned int i; } x; x.f = f;
    unsigned int r = (x.i + 0x7FFFu + ((x.i >> 16) & 1u)) >> 16;
    return (u16)r;
}
__device__ inline bf16x8 s2b(short8 v) {
    union { short8 s; bf16x8 b; } x; x.s = v; return x.b;
}

// async global->LDS, 16 B per lane.  LDS dest = wave-uniform base + lane*16.
__device__ inline void gload_lds16(const void* g, void* l) {
    __builtin_amdgcn_global_load_lds(
        (const __attribute__((address_space(1))) void*)g,
        (__attribute__((address_space(3))) void*)l, 16, 0, 0);
}

// XOR-swizzled fragment read from an unpadded [rows][64] u16 LDS buffer.
// One row = 128 B = all 32 banks; (r&7) XOR spreads 16-lane b128 reads.
__device__ inline bf16x8 ldsfrag(const u16* base, int r, int c) {
    return s2b(*(const short8*)&base[r * 64 + (c ^ ((r & 7) * 8))]);
}

__device__ inline void cvt8(const float* __restrict__ s, u16* __restrict__ d) {
    float4 a = *(const float4*)(s);
    float4 b = *(const float4*)(s + 4);
    union { u16 u[8]; int4 v; } o;
    o.u[0] = f2b_rn(a.x); o.u[1] = f2b_rn(a.y); o.u[2] = f2b_rn(a.z); o.u[3] = f2b_rn(a.w);
    o.u[4] = f2b_rn(b.x); o.u[5] = f2b_rn(b.y); o.u[6] = f2b_rn(b.z); o.u[7] = f2b_rn(b.w);
    *(int4*)(d) = o.v;
}

// ---------------------------------------------------------------------------
// Kernel P: prep.  blockIdx.x ranges:
//   [0,512)      x fp32->bf16   (4 x 2048 elems per block)
//   [512,1280)   W transpose+convert -> Wt[3072][1024]
//   [1280,5376)  mask -> bitmask (4096 blocks x 16 rows; 4 rows/wave)
// ---------------------------------------------------------------------------
__global__ __launch_bounds__(256) void prep(
    const float* __restrict__ x, const float* __restrict__ Wq,
    const float* __restrict__ Wk, const float* __restrict__ Wv,
    const int* __restrict__ mask,
    u16* __restrict__ xb, u16* __restrict__ Wt,
    unsigned long long* __restrict__ bits)
{
    __shared__ u16 T[64 * 80];
    int bx = blockIdx.x;
    int tid = threadIdx.x;

    if (bx < 512) {
        #pragma unroll
        for (int c = 0; c < 4; ++c) {
            int i = (bx * 4 + c) * 2048 + tid * 8;
            cvt8(x + i, xb + i);
        }
    } else if (bx < 1280) {
        int bx2 = bx - 512;
        int e0 = (bx2 & 15) * 64;
        int ph = bx2 >> 4;              // 0..47
        int p = ph >> 4, h = ph & 15;
        const float* W = (p == 0 ? Wq : (p == 1 ? Wk : Wv)) + h * (EMB * HD);
        #pragma unroll
        for (int c = 0; c < 2; ++c) {
            int flat = c * 2048 + tid * 8;
            int r = flat >> 6;
            int d = flat & 63;
            cvt8(W + (size_t)(e0 + r) * HD + d, &T[r * 80 + d]);
        }
        __syncthreads();
        int d = tid >> 2;
        int ec = tid & 3;
        union { u16 u[16]; int4 v[2]; } tmp;
        #pragma unroll
        for (int i = 0; i < 16; ++i) tmp.u[i] = T[(ec * 16 + i) * 80 + d];
        u16* dst = Wt + ((size_t)(p * NH + h) * HD + d) * EMB + e0 + ec * 16;
        *(int4*)(dst) = tmp.v[0];
        *(int4*)(dst + 8) = tmp.v[1];
    } else {
        int base = (bx - 1280) * 16 + (tid >> 6) * 4;    // 4 waves x 4 rows
        int lane = tid & 63;
        #pragma unroll
        for (int i = 0; i < 4; ++i) {
            int gw = base + i;                            // 0..65535
            int m = mask[(size_t)gw * 64 + lane];
            unsigned long long bl = __ballot(m != 0);
            if (lane == 0) bits[gw] = bl;
        }
    }
}

// ---------------------------------------------------------------------------
// Kernel 1: PURE fused QKV GEMM, m97 recipe.  XCD-PATCH mapping: xcd=id&7
// owns an 8-m-tile x 12-n-tile patch -> per-XCD working set = 2 MB x-rows
// + 0.75 MB Wt-rows = 2.75 MB < 4 MB L2 (old n+24*m mapping spread the
// full 14 MB working set across every XCD -> L3-latency re-reads).
// C[4096][3072] = x @ Wt^T (+bias); BK=64.  Q scaled by log2(e)/8;
// V written transposed Vt[b,h][d][s].
// ---------------------------------------------------------------------------
__global__ __launch_bounds__(256) void qkv_gemm(
    const u16* __restrict__ x,    // bf16 [4096][1024]
    const u16* __restrict__ Wt2,  // bf16 [3072][1024]
    const float* __restrict__ bq, const float* __restrict__ bk, const float* __restrict__ bv,
    u16* __restrict__ Q, u16* __restrict__ K, u16* __restrict__ Vt)
{
    __shared__ u16 As[128 * 64];
    __shared__ u16 Bs[128 * 64];

    int gid = blockIdx.x;
    // XCD-patch decode: xcd = gid&7 -> (mq, nq) quadrant; j = gid>>3 in-patch
    int xcd = gid & 7;            // 0..7
    int j   = gid >> 3;           // 0..95
    int mt_ = (xcd & 3) * 8 + (j & 7);        // m-tile 0..31
    int nt_ = (xcd >> 2) * 12 + (j >> 3);     // n-tile 0..23
    int m0 = mt_ * 128;
    int n0 = nt_ * 128;

    int tid = threadIdx.x;
    int w = tid >> 6, lane = tid & 63, quad = lane >> 4, ln = lane & 15;
    int wm = w & 1, wn = w >> 1;

    floatx4 acc[4][4] = {};

    for (int k0 = 0; k0 < EMB; k0 += 64) {
        __syncthreads();
        #pragma unroll
        for (int i = 0; i < 4; ++i) {
            int flat0 = i * 256 + (tid & 192);
            int flat = flat0 + lane;
            int r = flat >> 3;
            int c = ((flat & 7) ^ (r & 7)) * 8;
            gload_lds16(x   + (size_t)(m0 + r) * EMB + k0 + c, As + flat0 * 8);
            gload_lds16(Wt2 + (size_t)(n0 + r) * EMB + k0 + c, Bs + flat0 * 8);
        }
        __syncthreads();

        #pragma unroll
        for (int kk = 0; kk < 2; ++kk) {
            bf16x8 a[4], bf[4];
            #pragma unroll
            for (int mt = 0; mt < 4; ++mt)
                a[mt] = ldsfrag(As, wm * 64 + mt * 16 + ln, kk * 32 + quad * 8);
            #pragma unroll
            for (int nc = 0; nc < 4; ++nc)
                bf[nc] = ldsfrag(Bs, wn * 64 + nc * 16 + ln, kk * 32 + quad * 8);
            #pragma unroll
            for (int mt = 0; mt < 4; ++mt)
                #pragma unroll
                for (int nc = 0; nc < 4; ++nc)
                    acc[mt][nc] = __builtin_amdgcn_mfma_f32_16x16x32_bf16(a[mt], bf[nc], acc[mt][nc], 0, 0, 0);
        }
    }

    int p = n0 >> 10;
    const float* bias = (p == 0 ? bq : (p == 1 ? bk : bv));
    if (p < 2) {
        u16* Out = (p == 0) ? Q : K;
        float qs = (p == 0) ? 0.125f * 1.44269504f : 1.0f;   // fold 1/sqrt(64) and log2(e)
        #pragma unroll
        for (int nc = 0; nc < 4; ++nc) {
            int n = n0 + wn * 64 + nc * 16 + ln;
            int h = (n >> 6) & 15, d = n & 63;
            float bv_ = bias[n & 1023];
            #pragma unroll
            for (int mt = 0; mt < 4; ++mt) {
                #pragma unroll
                for (int reg = 0; reg < 4; ++reg) {
                    int m = m0 + wm * 64 + mt * 16 + quad * 4 + reg;
                    int b_ = m >> 10, s = m & 1023;
                    Out[((size_t)(b_ * NH + h) * SEQ + s) * HD + d] = f2b_rn((acc[mt][nc][reg] + bv_) * qs);
                }
            }
        }
    } else {
        #pragma unroll
        for (int nc = 0; nc < 4; ++nc) {
            int n = n0 + wn * 64 + nc * 16 + ln;
            int h = (n >> 6) & 15, d = n & 63;
            float bv_ = bias[n & 1023];
            #pragma unroll
            for (int mt = 0; mt < 4; ++mt) {
                int m = m0 + wm * 64 + mt * 16 + quad * 4;
                int b_ = m >> 10, s = m & 1023;
                union { u16 u[4]; uint2 v; } pk;
                #pragma unroll
                for (int reg = 0; reg < 4; ++reg)
                    pk.u[reg] = f2b_rn(acc[mt][nc][reg] + bv_);
                *(uint2*)&Vt[((size_t)(b_ * NH + h) * HD + d) * SEQ + s] = pk.v;
            }
        }
    }
}

// ---------------------------------------------------------------------------
// Kernel 2: flash attention v3 + Wo-convert tail blocks.  1D grid, 128 thr:
//   bid < 1024 : attn unit; bh = bid & 63 (same-(b,h) at stride 64 -> same
//                XCD, K/V 256 KB << 4 MB L2), q0 = (bid >> 6) * 64.
//   bid >= 1024: Wo fp32->bf16 tail (1024 blocks x 1024 elems).
// S^T = K Q^T: lane owns one softmax column; P = exp2 (Q carries log2e/8);
// l from a ones-row appended to V.
// ---------------------------------------------------------------------------
__global__ __launch_bounds__(128) void attn(
    const u16* __restrict__ Q, const u16* __restrict__ K, const u16* __restrict__ Vt,
    const unsigned long long* __restrict__ bits,
    const float* __restrict__ Wo, u16* __restrict__ Wob,
    u16* __restrict__ Aout)         // bf16 [B][S][E]
{
    const int PP = 72;  // Ps row stride in u16 (144 B)
    __shared__ u16 Ks[64 * 64];
    __shared__ u16 Vs[80 * 64];     // rows 0..63 = V^T tile, row 64 = ones
    __shared__ u16 Ps[64 * PP];

    int bid = blockIdx.x;
    int tid = threadIdx.x;

    if (bid >= 1024) {               // Wo convert tail
        int i = (bid - 1024) * 1024 + tid * 8;
        cvt8(Wo + i, Wob + i);
        return;
    }

    int bh = bid & 63;
    int q0 = (bid >> 6) * 64;
    int b = bh >> 4, h = bh & 15;
    const u16* Qb = Q  + (size_t)bh * SEQ * HD;
    const u16* Kb = K  + (size_t)bh * SEQ * HD;
    const u16* Vb = Vt + (size_t)bh * HD * SEQ;   // [d][s]

    int w = tid >> 6, lane = tid & 63, quad = lane >> 4, ln = lane & 15;

    if (tid < 16) *(uint2*)&Vs[64 * 64 + tid * 4] = make_uint2(0x3F803F80u, 0x3F803F80u);

    bf16x8 qf[2][2];
    #pragma unroll
    for (int s = 0; s < 2; ++s) {
        const u16* qp = Qb + (size_t)(q0 + w * 32 + s * 16 + ln) * HD + quad * 8;
        union { int4 i; bf16x8 b; } c0, c1;
        c0.i = *(const int4*)(qp);
        c1.i = *(const int4*)(qp + 32);
        qf[s][0] = c0.b; qf[s][1] = c1.b;
    }

    floatx4 o[2][5] = {};   // [strip][dt], dt=4 is the l column

    for (int tt = 0; tt < SEQ / 64; ++tt) {
        int t0 = tt * 64;
        __syncthreads();
        #pragma unroll
        for (int i = 0; i < 4; ++i) {
            int flat0 = i * 128 + (tid & 64);
            int flat = flat0 + lane;
            int r = flat >> 3;
            int c = ((flat & 7) ^ (r & 7)) * 8;
            gload_lds16(Kb + (size_t)(t0 + r) * HD + c, Ks + flat0 * 8);
            gload_lds16(Vb + (size_t)r * SEQ + t0 + c, Vs + flat0 * 8);
        }
        __syncthreads();

        // S^T = K Q^T : rows t, cols m
        floatx4 sc[2][4] = {};
        #pragma unroll
        for (int kk = 0; kk < 2; ++kk) {
            bf16x8 kf[4];
            #pragma unroll
            for (int tb = 0; tb < 4; ++tb)
                kf[tb] = ldsfrag(Ks, tb * 16 + ln, kk * 32 + quad * 8);
            #pragma unroll
            for (int s = 0; s < 2; ++s)
                #pragma unroll
                for (int tb = 0; tb < 4; ++tb)
                    sc[s][tb] = __builtin_amdgcn_mfma_f32_16x16x32_bf16(kf[tb], qf[s][kk], sc[s][tb], 0, 0, 0);
        }

        #pragma unroll
        for (int s = 0; s < 2; ++s) {
            unsigned long long bm = bits[((size_t)b * SEQ + q0 + w * 32 + s * 16 + ln) * 16 + tt];
            if (__any(bm != ~0ull)) {
                #pragma unroll
                for (int tb = 0; tb < 4; ++tb)
                    #pragma unroll
                    for (int reg = 0; reg < 4; ++reg)
                        if (!((bm >> (tb * 16 + quad * 4 + reg)) & 1)) sc[s][tb][reg] = -1e30f;
            }
        }

        // P = exp2(S), pack 4 consecutive t -> b64 LDS write
        #pragma unroll
        for (int s = 0; s < 2; ++s) {
            int mrow = w * 32 + s * 16 + ln;
            #pragma unroll
            for (int tb = 0; tb < 4; ++tb) {
                union { float f; unsigned int i; } e0_, e1_, e2_, e3_;
                e0_.f = __builtin_amdgcn_exp2f(sc[s][tb][0]);
                e1_.f = __builtin_amdgcn_exp2f(sc[s][tb][1]);
                e2_.f = __builtin_amdgcn_exp2f(sc[s][tb][2]);
                e3_.f = __builtin_amdgcn_exp2f(sc[s][tb][3]);
                uint2 pk;
                pk.x = ((e0_.i + 0x8000u) >> 16) | ((e1_.i + 0x8000u) & 0xFFFF0000u);
                pk.y = ((e2_.i + 0x8000u) >> 16) | ((e3_.i + 0x8000u) & 0xFFFF0000u);
                *(uint2*)&Ps[mrow * PP + tb * 16 + quad * 4] = pk;
            }
        }

        // O += P V  (l accumulates in dt=4 via the ones row)
        #pragma unroll
        for (int kk = 0; kk < 2; ++kk) {
            bf16x8 vf[5];
            #pragma unroll
            for (int dt = 0; dt < 5; ++dt)
                vf[dt] = ldsfrag(Vs, dt * 16 + ln, kk * 32 + quad * 8);
            #pragma unroll
            for (int s = 0; s < 2; ++s) {
                bf16x8 pf = s2b(*(const short8*)&Ps[(w * 32 + s * 16 + ln) * PP + kk * 32 + quad * 8]);
                #pragma unroll
                for (int dt = 0; dt < 5; ++dt)
                    o[s][dt] = __builtin_amdgcn_mfma_f32_16x16x32_bf16(pf, vf[dt], o[s][dt], 0, 0, 0);
            }
        }
    }

    #pragma unroll
    for (int s = 0; s < 2; ++s) {
        #pragma unroll
        for (int reg = 0; reg < 4; ++reg) {
            float l = __shfl(o[s][4][reg], lane & 48, 64);
            float inv = 1.0f / l;
            int m = q0 + w * 32 + s * 16 + quad * 4 + reg;
            #pragma unroll
            for (int dt = 0; dt < 4; ++dt)
                Aout[((size_t)b * SEQ + m) * EMB + h * HD + dt * 16 + ln] = f2b_rn(o[s][dt][reg] * inv);
        }
    }
}

// ---------------------------------------------------------------------------
// Kernel 3: output projection.  64x128 tile, BK=64 single buffer, grid 512.
// XCD-patch mapping: xcd=id&7 owns 8 m-tiles x all 8 n-tiles -> per-XCD
// working set = 1 MB A-rows + 2 MB Wob = 3 MB < 4 MB L2.
// Out[4096][1024] fp32.
// ---------------------------------------------------------------------------
__global__ __launch_bounds__(256) void out_proj(
    const u16* __restrict__ A,    // bf16 [4096][1024]
    const u16* __restrict__ Wo,   // bf16 [1024][1024] (n,k)
    const float* __restrict__ bo,
    float* __restrict__ Out)
{
    __shared__ u16 As[64 * 64];
    __shared__ u16 Bs[128 * 64];

    int gid = blockIdx.x;
    int xcd = gid & 7;            // 0..7
    int j   = gid >> 3;           // 0..63
    int m0 = (xcd * 8 + (j & 7)) * 64;        // m-tile 0..63
    int n0 = (j >> 3) * 128;                  // n-tile 0..7

    int tid = threadIdx.x;
    int w = tid >> 6, lane = tid & 63, quad = lane >> 4, ln = lane & 15;
    int wm = w & 1, wn = w >> 1;

    floatx4 acc[2][4] = {};

    for (int k0 = 0; k0 < EMB; k0 += 64) {
        __syncthreads();
        #pragma unroll
        for (int i = 0; i < 2; ++i) {
            int flat0 = i * 256 + (tid & 192);
            int flat = flat0 + lane;
            int r = flat >> 3;                   // 0..63
            int c = ((flat & 7) ^ (r & 7)) * 8;
            gload_lds16(A + (size_t)(m0 + r) * EMB + k0 + c, As + flat0 * 8);
        }
        #pragma unroll
        for (int i = 0; i < 4; ++i) {
            int flat0 = i * 256 + (tid & 192);
            int flat = flat0 + lane;
            int r = flat >> 3;                   // 0..127
            int c = ((flat & 7) ^ (r & 7)) * 8;
            gload_lds16(Wo + (size_t)(n0 + r) * EMB + k0 + c, Bs + flat0 * 8);
        }
        __syncthreads();

        #pragma unroll
        for (int kk = 0; kk < 2; ++kk) {
            bf16x8 a[2], bfr[4];
            #pragma unroll
            for (int mt = 0; mt < 2; ++mt)
                a[mt] = ldsfrag(As, wm * 32 + mt * 16 + ln, kk * 32 + quad * 8);
            #pragma unroll
            for (int nc = 0; nc < 4; ++nc)
                bfr[nc] = ldsfrag(Bs, wn * 64 + nc * 16 + ln, kk * 32 + quad * 8);
            #pragma unroll
            for (int mt = 0; mt < 2; ++mt)
                #pragma unroll
                for (int nc = 0; nc < 4; ++nc)
                    acc[mt][nc] = __builtin_amdgcn_mfma_f32_16x16x32_bf16(a[mt], bfr[nc], acc[mt][nc], 0, 0, 0);
        }
    }

    #pragma unroll
    for (int nc = 0; nc < 4; ++nc) {
        int n = n0 + wn * 64 + nc * 16 + ln;
        float bb = bo[n];
        #pragma unroll
        for (int mt = 0; mt < 2; ++mt) {
            #pragma unroll
            for (int reg = 0; reg < 4; ++reg) {
                int m = m0 + wm * 32 + mt * 16 + quad * 4 + reg;
                Out[(size_t)m * EMB + n] = acc[mt][nc][reg] + bb;
            }
        }
    }
}

// ---------------------------------------------------------------------------
extern "C" void kernel_launch(void* const* d_in, const int* in_sizes, int n_in,
                              void* d_out, int out_size, void* d_ws, size_t ws_size,
                              hipStream_t stream) {
    const float* x  = (const float*)d_in[0];
    const int*   mk = (const int*)d_in[1];
    const float* Wq = (const float*)d_in[2];
    const float* bq = (const float*)d_in[3];
    const float* Wk = (const float*)d_in[4];
    const float* bk = (const float*)d_in[5];
    const float* Wv = (const float*)d_in[6];
    const float* bv = (const float*)d_in[7];
    const float* Wo = (const float*)d_in[8];
    const float* bo = (const float*)d_in[9];
    float* out = (float*)d_out;

    const size_t MB = 1u << 20;
    char* ws = (char*)d_ws;
    u16* xb  = (u16*)ws;                                   // [ 0, 8M)
    u16* Wt  = (u16*)(ws + 8 * MB);                        // [ 8,14M)
    u16* Wob = (u16*)(ws + 14 * MB);                       // [14,16M)
    unsigned long long* bits = (unsigned long long*)(ws + 16 * MB); // [16,16.5M)
    u16* Qw  = (u16*)(ws + 16 * MB + 512 * 1024);          // [16.5,24.5M)
    u16* Kw  = (u16*)(ws + 24 * MB + 512 * 1024);          // [24.5,32.5M)
    u16* Vtw = (u16*)(ws + 32 * MB + 512 * 1024);          // [32.5,40.5M)
    u16* Ao  = xb;                                         // reuse: xb dead after qkv

    prep<<<5376, 256, 0, stream>>>(x, Wq, Wk, Wv, mk, xb, Wt, bits);
    qkv_gemm<<<768, 256, 0, stream>>>(xb, Wt, bq, bk, bv, Qw, Kw, Vtw);
    attn<<<2048, 128, 0, stream>>>(Qw, Kw, Vtw, bits, Wo, Wob, Ao);
    out_proj<<<512, 256, 0, stream>>>(Ao, Wob, bo, out);
}

// Round 17
// 192.277 us; speedup vs baseline: 2.5290x; 1.0107x over previous
//
#include <hip/hip_runtime.h>
#include <hip/hip_bf16.h>

#define NB 4       // batch
#define SEQ 1024
#define EMB 1024
#define NH 16
#define HD 64

typedef unsigned short u16;
typedef __attribute__((ext_vector_type(8))) __bf16 bf16x8;
typedef __attribute__((ext_vector_type(8))) short short8;
typedef __attribute__((ext_vector_type(4))) float floatx4;

// fp32 -> bf16 round-to-nearest-even
__device__ inline u16 f2b_rn(float f) {
    union { float f; unsigned int i; } x; x.f = f;
    unsigned int r = (x.i + 0x7FFFu + ((x.i >> 16) & 1u)) >> 16;
    return (u16)r;
}
__device__ inline bf16x8 s2b(short8 v) {
    union { short8 s; bf16x8 b; } x; x.s = v; return x.b;
}

// async global->LDS, 16 B per lane.  LDS dest = wave-uniform base + lane*16.
__device__ inline void gload_lds16(const void* g, void* l) {
    __builtin_amdgcn_global_load_lds(
        (const __attribute__((address_space(1))) void*)g,
        (__attribute__((address_space(3))) void*)l, 16, 0, 0);
}

// XOR-swizzled fragment read from an unpadded [rows][64] u16 LDS buffer.
// One row = 128 B = all 32 banks; (r&7) XOR spreads 16-lane b128 reads.
__device__ inline bf16x8 ldsfrag(const u16* base, int r, int c) {
    return s2b(*(const short8*)&base[r * 64 + (c ^ ((r & 7) * 8))]);
}

__device__ inline void cvt8(const float* __restrict__ s, u16* __restrict__ d) {
    float4 a = *(const float4*)(s);
    float4 b = *(const float4*)(s + 4);
    union { u16 u[8]; int4 v; } o;
    o.u[0] = f2b_rn(a.x); o.u[1] = f2b_rn(a.y); o.u[2] = f2b_rn(a.z); o.u[3] = f2b_rn(a.w);
    o.u[4] = f2b_rn(b.x); o.u[5] = f2b_rn(b.y); o.u[6] = f2b_rn(b.z); o.u[7] = f2b_rn(b.w);
    *(int4*)(d) = o.v;
}

// ---------------------------------------------------------------------------
// Kernel P: prep.  blockIdx.x ranges:
//   [0,512)      x fp32->bf16   (4 x 2048 elems per block)
//   [512,1280)   W transpose+convert -> Wt[3072][1024]
//   [1280,5376)  mask -> bitmask (4096 blocks x 16 rows; 4 rows/wave)
// ---------------------------------------------------------------------------
__global__ __launch_bounds__(256) void prep(
    const float* __restrict__ x, const float* __restrict__ Wq,
    const float* __restrict__ Wk, const float* __restrict__ Wv,
    const int* __restrict__ mask,
    u16* __restrict__ xb, u16* __restrict__ Wt,
    unsigned long long* __restrict__ bits)
{
    __shared__ u16 T[64 * 80];
    int bx = blockIdx.x;
    int tid = threadIdx.x;

    if (bx < 512) {
        #pragma unroll
        for (int c = 0; c < 4; ++c) {
            int i = (bx * 4 + c) * 2048 + tid * 8;
            cvt8(x + i, xb + i);
        }
    } else if (bx < 1280) {
        int bx2 = bx - 512;
        int e0 = (bx2 & 15) * 64;
        int ph = bx2 >> 4;              // 0..47
        int p = ph >> 4, h = ph & 15;
        const float* W = (p == 0 ? Wq : (p == 1 ? Wk : Wv)) + h * (EMB * HD);
        #pragma unroll
        for (int c = 0; c < 2; ++c) {
            int flat = c * 2048 + tid * 8;
            int r = flat >> 6;
            int d = flat & 63;
            cvt8(W + (size_t)(e0 + r) * HD + d, &T[r * 80 + d]);
        }
        __syncthreads();
        int d = tid >> 2;
        int ec = tid & 3;
        union { u16 u[16]; int4 v[2]; } tmp;
        #pragma unroll
        for (int i = 0; i < 16; ++i) tmp.u[i] = T[(ec * 16 + i) * 80 + d];
        u16* dst = Wt + ((size_t)(p * NH + h) * HD + d) * EMB + e0 + ec * 16;
        *(int4*)(dst) = tmp.v[0];
        *(int4*)(dst + 8) = tmp.v[1];
    } else {
        int base = (bx - 1280) * 16 + (tid >> 6) * 4;    // 4 waves x 4 rows
        int lane = tid & 63;
        #pragma unroll
        for (int i = 0; i < 4; ++i) {
            int gw = base + i;                            // 0..65535
            int m = mask[(size_t)gw * 64 + lane];
            unsigned long long bl = __ballot(m != 0);
            if (lane == 0) bits[gw] = bl;
        }
    }
}

// ---------------------------------------------------------------------------
// Kernel 1: PURE fused QKV GEMM, m97 recipe.  XCD-PATCH mapping: xcd=id&7
// owns an 8-m-tile x 12-n-tile patch -> per-XCD working set 2.75 MB < 4 MB
// L2 (measured r16: FETCH 40->28.8 MB, 59->48 us).
// C[4096][3072] = x @ Wt^T (+bias); BK=64.  Q scaled by log2(e)/8;
// V written transposed Vt[b,h][d][s].
// ---------------------------------------------------------------------------
__global__ __launch_bounds__(256) void qkv_gemm(
    const u16* __restrict__ x,    // bf16 [4096][1024]
    const u16* __restrict__ Wt2,  // bf16 [3072][1024]
    const float* __restrict__ bq, const float* __restrict__ bk, const float* __restrict__ bv,
    u16* __restrict__ Q, u16* __restrict__ K, u16* __restrict__ Vt)
{
    __shared__ u16 As[128 * 64];
    __shared__ u16 Bs[128 * 64];

    int gid = blockIdx.x;
    int xcd = gid & 7;            // 0..7
    int j   = gid >> 3;           // 0..95
    int mt_ = (xcd & 3) * 8 + (j & 7);        // m-tile 0..31
    int nt_ = (xcd >> 2) * 12 + (j >> 3);     // n-tile 0..23
    int m0 = mt_ * 128;
    int n0 = nt_ * 128;

    int tid = threadIdx.x;
    int w = tid >> 6, lane = tid & 63, quad = lane >> 4, ln = lane & 15;
    int wm = w & 1, wn = w >> 1;

    floatx4 acc[4][4] = {};

    for (int k0 = 0; k0 < EMB; k0 += 64) {
        __syncthreads();
        #pragma unroll
        for (int i = 0; i < 4; ++i) {
            int flat0 = i * 256 + (tid & 192);
            int flat = flat0 + lane;
            int r = flat >> 3;
            int c = ((flat & 7) ^ (r & 7)) * 8;
            gload_lds16(x   + (size_t)(m0 + r) * EMB + k0 + c, As + flat0 * 8);
            gload_lds16(Wt2 + (size_t)(n0 + r) * EMB + k0 + c, Bs + flat0 * 8);
        }
        __syncthreads();

        #pragma unroll
        for (int kk = 0; kk < 2; ++kk) {
            bf16x8 a[4], bf[4];
            #pragma unroll
            for (int mt = 0; mt < 4; ++mt)
                a[mt] = ldsfrag(As, wm * 64 + mt * 16 + ln, kk * 32 + quad * 8);
            #pragma unroll
            for (int nc = 0; nc < 4; ++nc)
                bf[nc] = ldsfrag(Bs, wn * 64 + nc * 16 + ln, kk * 32 + quad * 8);
            #pragma unroll
            for (int mt = 0; mt < 4; ++mt)
                #pragma unroll
                for (int nc = 0; nc < 4; ++nc)
                    acc[mt][nc] = __builtin_amdgcn_mfma_f32_16x16x32_bf16(a[mt], bf[nc], acc[mt][nc], 0, 0, 0);
        }
    }

    int p = n0 >> 10;
    const float* bias = (p == 0 ? bq : (p == 1 ? bk : bv));
    if (p < 2) {
        u16* Out = (p == 0) ? Q : K;
        float qs = (p == 0) ? 0.125f * 1.44269504f : 1.0f;   // fold 1/sqrt(64) and log2(e)
        #pragma unroll
        for (int nc = 0; nc < 4; ++nc) {
            int n = n0 + wn * 64 + nc * 16 + ln;
            int h = (n >> 6) & 15, d = n & 63;
            float bv_ = bias[n & 1023];
            #pragma unroll
            for (int mt = 0; mt < 4; ++mt) {
                #pragma unroll
                for (int reg = 0; reg < 4; ++reg) {
                    int m = m0 + wm * 64 + mt * 16 + quad * 4 + reg;
                    int b_ = m >> 10, s = m & 1023;
                    Out[((size_t)(b_ * NH + h) * SEQ + s) * HD + d] = f2b_rn((acc[mt][nc][reg] + bv_) * qs);
                }
            }
        }
    } else {
        #pragma unroll
        for (int nc = 0; nc < 4; ++nc) {
            int n = n0 + wn * 64 + nc * 16 + ln;
            int h = (n >> 6) & 15, d = n & 63;
            float bv_ = bias[n & 1023];
            #pragma unroll
            for (int mt = 0; mt < 4; ++mt) {
                int m = m0 + wm * 64 + mt * 16 + quad * 4;
                int b_ = m >> 10, s = m & 1023;
                union { u16 u[4]; uint2 v; } pk;
                #pragma unroll
                for (int reg = 0; reg < 4; ++reg)
                    pk.u[reg] = f2b_rn(acc[mt][nc][reg] + bv_);
                *(uint2*)&Vt[((size_t)(b_ * NH + h) * HD + d) * SEQ + s] = pk.v;
            }
        }
    }
}

// ---------------------------------------------------------------------------
// Kernel 2: flash attention v6 — 128-row q-tiles (r13-P2 structure, proven
// correct there, measured standalone here).  1D grid, 256 thr = 4 waves:
//   bid < 512 : attn unit; bh = bid & 63, q0 = (bid >> 6) * 128.  4 waves
//               share ONE K/V staging per 128 q-rows (vs v3: per 64) —
//               halves K/V traffic, barriers, and staging insts per q-row.
//               Each wave owns 2 strips of 16 rows (keeps v3's fragment
//               amortization; avoids r7-v4's 1-strip amplification).
//   bid >= 512: Wo fp32->bf16 tail (512 blocks x 2048 elems).
// S^T = K Q^T: lane owns one softmax column; P = exp2 (Q carries log2e/8);
// l from a ones-row appended to V.  LDS 36 KB -> 4 blocks/CU.
// ---------------------------------------------------------------------------
__global__ __launch_bounds__(256) void attn(
    const u16* __restrict__ Q, const u16* __restrict__ K, const u16* __restrict__ Vt,
    const unsigned long long* __restrict__ bits,
    const float* __restrict__ Wo, u16* __restrict__ Wob,
    u16* __restrict__ Aout)         // bf16 [B][S][E]
{
    const int PP = 72;  // Ps row stride in u16 (144 B)
    __shared__ u16 Ks[64 * 64];
    __shared__ u16 Vs[80 * 64];     // rows 0..63 = V^T tile, row 64 = ones
    __shared__ u16 Ps[128 * PP];

    int bid = blockIdx.x;
    int tid = threadIdx.x;

    if (bid >= 512) {                // Wo convert tail
        int i = (bid - 512) * 2048 + tid * 8;
        cvt8(Wo + i, Wob + i);
        return;
    }

    int bh = bid & 63;
    int q0 = (bid >> 6) * 128;
    int b = bh >> 4, h = bh & 15;
    const u16* Qb = Q  + (size_t)bh * SEQ * HD;
    const u16* Kb = K  + (size_t)bh * SEQ * HD;
    const u16* Vb = Vt + (size_t)bh * HD * SEQ;   // [d][s]

    int w = tid >> 6, lane = tid & 63, quad = lane >> 4, ln = lane & 15;

    if (tid < 16) *(uint2*)&Vs[64 * 64 + tid * 4] = make_uint2(0x3F803F80u, 0x3F803F80u);

    // Q B-fragments: wave w owns strips (w*32 .. w*32+31), 2 strips of 16
    bf16x8 qf[2][2];
    #pragma unroll
    for (int s = 0; s < 2; ++s) {
        const u16* qp = Qb + (size_t)(q0 + w * 32 + s * 16 + ln) * HD + quad * 8;
        union { int4 i; bf16x8 b; } c0, c1;
        c0.i = *(const int4*)(qp);
        c1.i = *(const int4*)(qp + 32);
        qf[s][0] = c0.b; qf[s][1] = c1.b;
    }

    floatx4 o[2][5] = {};   // [strip][dt], dt=4 is the l column

    for (int tt = 0; tt < SEQ / 64; ++tt) {
        int t0 = tt * 64;
        __syncthreads();
        #pragma unroll
        for (int i = 0; i < 2; ++i) {
            int flat0 = i * 256 + (tid & 192);
            int flat = flat0 + lane;
            int r = flat >> 3;
            int c = ((flat & 7) ^ (r & 7)) * 8;
            gload_lds16(Kb + (size_t)(t0 + r) * HD + c, Ks + flat0 * 8);
            gload_lds16(Vb + (size_t)r * SEQ + t0 + c, Vs + flat0 * 8);
        }
        __syncthreads();

        // S^T = K Q^T : rows t, cols m (this wave's 32 m-columns)
        floatx4 sc[2][4] = {};
        #pragma unroll
        for (int kk = 0; kk < 2; ++kk) {
            bf16x8 kf[4];
            #pragma unroll
            for (int tb = 0; tb < 4; ++tb)
                kf[tb] = ldsfrag(Ks, tb * 16 + ln, kk * 32 + quad * 8);
            #pragma unroll
            for (int s = 0; s < 2; ++s)
                #pragma unroll
                for (int tb = 0; tb < 4; ++tb)
                    sc[s][tb] = __builtin_amdgcn_mfma_f32_16x16x32_bf16(kf[tb], qf[s][kk], sc[s][tb], 0, 0, 0);
        }

        #pragma unroll
        for (int s = 0; s < 2; ++s) {
            unsigned long long bm = bits[((size_t)b * SEQ + q0 + w * 32 + s * 16 + ln) * 16 + tt];
            if (__any(bm != ~0ull)) {
                #pragma unroll
                for (int tb = 0; tb < 4; ++tb)
                    #pragma unroll
                    for (int reg = 0; reg < 4; ++reg)
                        if (!((bm >> (tb * 16 + quad * 4 + reg)) & 1)) sc[s][tb][reg] = -1e30f;
            }
        }

        // P = exp2(S), pack 4 consecutive t -> b64 LDS write (per-wave rows)
        #pragma unroll
        for (int s = 0; s < 2; ++s) {
            int mrow = w * 32 + s * 16 + ln;
            #pragma unroll
            for (int tb = 0; tb < 4; ++tb) {
                union { float f; unsigned int i; } e0_, e1_, e2_, e3_;
                e0_.f = __builtin_amdgcn_exp2f(sc[s][tb][0]);
                e1_.f = __builtin_amdgcn_exp2f(sc[s][tb][1]);
                e2_.f = __builtin_amdgcn_exp2f(sc[s][tb][2]);
                e3_.f = __builtin_amdgcn_exp2f(sc[s][tb][3]);
                uint2 pk;
                pk.x = ((e0_.i + 0x8000u) >> 16) | ((e1_.i + 0x8000u) & 0xFFFF0000u);
                pk.y = ((e2_.i + 0x8000u) >> 16) | ((e3_.i + 0x8000u) & 0xFFFF0000u);
                *(uint2*)&Ps[mrow * PP + tb * 16 + quad * 4] = pk;
            }
        }

        // O += P V  (l accumulates in dt=4 via the ones row)
        #pragma unroll
        for (int kk = 0; kk < 2; ++kk) {
            bf16x8 vf[5];
            #pragma unroll
            for (int dt = 0; dt < 5; ++dt)
                vf[dt] = ldsfrag(Vs, dt * 16 + ln, kk * 32 + quad * 8);
            #pragma unroll
            for (int s = 0; s < 2; ++s) {
                bf16x8 pf = s2b(*(const short8*)&Ps[(w * 32 + s * 16 + ln) * PP + kk * 32 + quad * 8]);
                #pragma unroll
                for (int dt = 0; dt < 5; ++dt)
                    o[s][dt] = __builtin_amdgcn_mfma_f32_16x16x32_bf16(pf, vf[dt], o[s][dt], 0, 0, 0);
            }
        }
    }

    #pragma unroll
    for (int s = 0; s < 2; ++s) {
        #pragma unroll
        for (int reg = 0; reg < 4; ++reg) {
            float l = __shfl(o[s][4][reg], lane & 48, 64);
            float inv = 1.0f / l;
            int m = q0 + w * 32 + s * 16 + quad * 4 + reg;
            #pragma unroll
            for (int dt = 0; dt < 4; ++dt)
                Aout[((size_t)b * SEQ + m) * EMB + h * HD + dt * 16 + ln] = f2b_rn(o[s][dt][reg] * inv);
        }
    }
}

// ---------------------------------------------------------------------------
// Kernel 3: output projection.  64x128 tile, BK=64 single buffer, grid 512.
// XCD-patch mapping: xcd=id&7 owns 8 m-tiles x all 8 n-tiles (3 MB < L2).
// Out[4096][1024] fp32.
// ---------------------------------------------------------------------------
__global__ __launch_bounds__(256) void out_proj(
    const u16* __restrict__ A,    // bf16 [4096][1024]
    const u16* __restrict__ Wo,   // bf16 [1024][1024] (n,k)
    const float* __restrict__ bo,
    float* __restrict__ Out)
{
    __shared__ u16 As[64 * 64];
    __shared__ u16 Bs[128 * 64];

    int gid = blockIdx.x;
    int xcd = gid & 7;            // 0..7
    int j   = gid >> 3;           // 0..63
    int m0 = (xcd * 8 + (j & 7)) * 64;        // m-tile 0..63
    int n0 = (j >> 3) * 128;                  // n-tile 0..7

    int tid = threadIdx.x;
    int w = tid >> 6, lane = tid & 63, quad = lane >> 4, ln = lane & 15;
    int wm = w & 1, wn = w >> 1;

    floatx4 acc[2][4] = {};

    for (int k0 = 0; k0 < EMB; k0 += 64) {
        __syncthreads();
        #pragma unroll
        for (int i = 0; i < 2; ++i) {
            int flat0 = i * 256 + (tid & 192);
            int flat = flat0 + lane;
            int r = flat >> 3;                   // 0..63
            int c = ((flat & 7) ^ (r & 7)) * 8;
            gload_lds16(A + (size_t)(m0 + r) * EMB + k0 + c, As + flat0 * 8);
        }
        #pragma unroll
        for (int i = 0; i < 4; ++i) {
            int flat0 = i * 256 + (tid & 192);
            int flat = flat0 + lane;
            int r = flat >> 3;                   // 0..127
            int c = ((flat & 7) ^ (r & 7)) * 8;
            gload_lds16(Wo + (size_t)(n0 + r) * EMB + k0 + c, Bs + flat0 * 8);
        }
        __syncthreads();

        #pragma unroll
        for (int kk = 0; kk < 2; ++kk) {
            bf16x8 a[2], bfr[4];
            #pragma unroll
            for (int mt = 0; mt < 2; ++mt)
                a[mt] = ldsfrag(As, wm * 32 + mt * 16 + ln, kk * 32 + quad * 8);
            #pragma unroll
            for (int nc = 0; nc < 4; ++nc)
                bfr[nc] = ldsfrag(Bs, wn * 64 + nc * 16 + ln, kk * 32 + quad * 8);
            #pragma unroll
            for (int mt = 0; mt < 2; ++mt)
                #pragma unroll
                for (int nc = 0; nc < 4; ++nc)
                    acc[mt][nc] = __builtin_amdgcn_mfma_f32_16x16x32_bf16(a[mt], bfr[nc], acc[mt][nc], 0, 0, 0);
        }
    }

    #pragma unroll
    for (int nc = 0; nc < 4; ++nc) {
        int n = n0 + wn * 64 + nc * 16 + ln;
        float bb = bo[n];
        #pragma unroll
        for (int mt = 0; mt < 2; ++mt) {
            #pragma unroll
            for (int reg = 0; reg < 4; ++reg) {
                int m = m0 + wm * 32 + mt * 16 + quad * 4 + reg;
                Out[(size_t)m * EMB + n] = acc[mt][nc][reg] + bb;
            }
        }
    }
}

// ---------------------------------------------------------------------------
extern "C" void kernel_launch(void* const* d_in, const int* in_sizes, int n_in,
                              void* d_out, int out_size, void* d_ws, size_t ws_size,
                              hipStream_t stream) {
    const float* x  = (const float*)d_in[0];
    const int*   mk = (const int*)d_in[1];
    const float* Wq = (const float*)d_in[2];
    const float* bq = (const float*)d_in[3];
    const float* Wk = (const float*)d_in[4];
    const float* bk = (const float*)d_in[5];
    const float* Wv = (const float*)d_in[6];
    const float* bv = (const float*)d_in[7];
    const float* Wo = (const float*)d_in[8];
    const float* bo = (const float*)d_in[9];
    float* out = (float*)d_out;

    const size_t MB = 1u << 20;
    char* ws = (char*)d_ws;
    u16* xb  = (u16*)ws;                                   // [ 0, 8M)
    u16* Wt  = (u16*)(ws + 8 * MB);                        // [ 8,14M)
    u16* Wob = (u16*)(ws + 14 * MB);                       // [14,16M)
    unsigned long long* bits = (unsigned long long*)(ws + 16 * MB); // [16,16.5M)
    u16* Qw  = (u16*)(ws + 16 * MB + 512 * 1024);          // [16.5,24.5M)
    u16* Kw  = (u16*)(ws + 24 * MB + 512 * 1024);          // [24.5,32.5M)
    u16* Vtw = (u16*)(ws + 32 * MB + 512 * 1024);          // [32.5,40.5M)
    u16* Ao  = xb;                                         // reuse: xb dead after qkv

    prep<<<5376, 256, 0, stream>>>(x, Wq, Wk, Wv, mk, xb, Wt, bits);
    qkv_gemm<<<768, 256, 0, stream>>>(xb, Wt, bq, bk, bv, Qw, Kw, Vtw);
    attn<<<1024, 256, 0, stream>>>(Qw, Kw, Vtw, bits, Wo, Wob, Ao);
    out_proj<<<512, 256, 0, stream>>>(Ao, Wob, bo, out);
}